// Round 8
// baseline (350.276 us; speedup 1.0000x reference)
//
#include <hip/hip_runtime.h>
#include <hip/hip_bf16.h>

#define D_MODEL 1024
#define NUM_HEADS 16
#define D_K 64
#define S_LEN 2048
#define BATCH 4

typedef unsigned short u16;
typedef __attribute__((ext_vector_type(8))) short bf16x8;
typedef __attribute__((ext_vector_type(4))) float f32x4;

#define MFMA16 __builtin_amdgcn_mfma_f32_16x16x32_bf16

// fold attn scale + ln2 conversion into the Q projection: 0.125 * log2(e)
#define Q_SCALE 0.18033688011112042f

__device__ __forceinline__ float bf2f(u16 u) {
    union { unsigned int i; float f; } v; v.i = ((unsigned int)u) << 16; return v.f;
}
__device__ __forceinline__ u16 f2bf(float f) {
    union { unsigned int i; float f; } v; v.f = f;
    unsigned int x = v.i;
    return (u16)((x + 0x7FFFu + ((x >> 16) & 1u)) >> 16); // round-nearest-even
}
// packed f32x2 -> bf16x2 (RNE), single HW op
__device__ __forceinline__ unsigned int cvtpk(float lo, float hi) {
    unsigned int r;
    asm("v_cvt_pk_bf16_f32 %0, %1, %2" : "=v"(r) : "v"(lo), "v"(hi));
    return r;
}

__device__ __forceinline__ void gload16(const u16* g, u16* l) {
    __builtin_amdgcn_global_load_lds(
        (const __attribute__((address_space(1))) unsigned int*)g,
        (__attribute__((address_space(3))) unsigned int*)l, 16, 0, 0);
}

// ---------------- prep: x fp32 -> bf16 ----------------
__global__ __launch_bounds__(256) void convert_x(
    const float* __restrict__ x, u16* __restrict__ xb)
{
    const size_t i = ((size_t)blockIdx.x * 256 + threadIdx.x) * 8;
    float4 a = *reinterpret_cast<const float4*>(x + i);
    float4 b = *reinterpret_cast<const float4*>(x + i + 4);
    bf16x8 o;
    o[0] = (short)f2bf(a.x); o[1] = (short)f2bf(a.y);
    o[2] = (short)f2bf(a.z); o[3] = (short)f2bf(a.w);
    o[4] = (short)f2bf(b.x); o[5] = (short)f2bf(b.y);
    o[6] = (short)f2bf(b.z); o[7] = (short)f2bf(b.w);
    *reinterpret_cast<bf16x8*>(xb + i) = o;
}

// ---------------- prep: W[k][n] fp32 -> WT[n][k] bf16 (4 matrices) ----------------
__global__ __launch_bounds__(256) void transpose_w(
    const float* __restrict__ W0, const float* __restrict__ W1,
    const float* __restrict__ W2, const float* __restrict__ W3,
    u16* __restrict__ T0, u16* __restrict__ T1,
    u16* __restrict__ T2, u16* __restrict__ T3)
{
    const float* W; u16* T;
    switch (blockIdx.z & 3) {
        case 0:  W = W0; T = T0; break;
        case 1:  W = W1; T = T1; break;
        case 2:  W = W2; T = T2; break;
        default: W = W3; T = T3; break;
    }
    __shared__ u16 S[64][72];
    const int tid = threadIdx.x;
    const int k0 = blockIdx.y * 64, n0 = blockIdx.x * 64;

    const int k = tid >> 2, nb = (tid & 3) * 16;
    #pragma unroll
    for (int c = 0; c < 4; ++c) {
        float4 v = *reinterpret_cast<const float4*>(
            W + (size_t)(k0 + k) * D_MODEL + n0 + nb + c * 4);
        S[nb + c * 4 + 0][k] = f2bf(v.x);
        S[nb + c * 4 + 1][k] = f2bf(v.y);
        S[nb + c * 4 + 2][k] = f2bf(v.z);
        S[nb + c * 4 + 3][k] = f2bf(v.w);
    }
    __syncthreads();
    const int n = tid >> 2, kb = (tid & 3) * 16;
    #pragma unroll
    for (int c = 0; c < 2; ++c) {
        bf16x8 o;
        #pragma unroll
        for (int e = 0; e < 8; ++e) o[e] = (short)S[n][kb + c * 8 + e];
        *reinterpret_cast<bf16x8*>(T + (size_t)(n0 + n) * D_MODEL + k0 + kb + c * 8) = o;
    }
}

// ---------------- MFMA GEMM: C = A[8192,1024] @ BT[1024,1024]^T + bias, then *oscale ----------------
template <typename TC>
__device__ __forceinline__ void gemm_body(
    const u16* __restrict__ A, const u16* __restrict__ BT,
    const float* __restrict__ bias, TC* __restrict__ C,
    u16* Al, u16* Bl, float oscale)
{
    const int tid = threadIdx.x;
    const int w = tid >> 6, lane = tid & 63;
    const int g = lane >> 4, c16 = lane & 15;
    const int wr = w >> 1, wc = w & 1;
    const int m0 = blockIdx.y * 128, n0 = blockIdx.x * 128;

    int rS[4], uS[4];
    #pragma unroll
    for (int i = 0; i < 4; ++i) {
        const int p = i * 256 + tid;
        rS[i] = p >> 3;
        uS[i] = ((p & 7) ^ (rS[i] & 7)) * 8;
    }

    f32x4 acc[4][4];
    #pragma unroll
    for (int mi = 0; mi < 4; ++mi)
        #pragma unroll
        for (int ni = 0; ni < 4; ++ni) acc[mi][ni] = (f32x4){0.f, 0.f, 0.f, 0.f};

    for (int k0 = 0; k0 < D_MODEL; k0 += 64) {
        #pragma unroll
        for (int i = 0; i < 4; ++i) {
            gload16(A + (size_t)(m0 + rS[i]) * D_MODEL + k0 + uS[i],
                    Al + (size_t)(i * 256 + w * 64) * 8);
            gload16(BT + (size_t)(n0 + rS[i]) * D_MODEL + k0 + uS[i],
                    Bl + (size_t)(i * 256 + w * 64) * 8);
        }
        __syncthreads();

        #pragma unroll
        for (int s = 0; s < 2; ++s) {
            bf16x8 af[4], bfr[4];
            #pragma unroll
            for (int mi = 0; mi < 4; ++mi) {
                const int r = wr * 64 + mi * 16 + c16;
                af[mi] = *reinterpret_cast<const bf16x8*>(
                    &Al[((r << 3) + ((s * 4 + g) ^ (r & 7))) * 8]);
            }
            #pragma unroll
            for (int ni = 0; ni < 4; ++ni) {
                const int r = wc * 64 + ni * 16 + c16;
                bfr[ni] = *reinterpret_cast<const bf16x8*>(
                    &Bl[((r << 3) + ((s * 4 + g) ^ (r & 7))) * 8]);
            }
            #pragma unroll
            for (int mi = 0; mi < 4; ++mi)
                #pragma unroll
                for (int ni = 0; ni < 4; ++ni)
                    acc[mi][ni] = MFMA16(af[mi], bfr[ni], acc[mi][ni], 0, 0, 0);
        }
        __syncthreads();
    }

    float bc[4];
    #pragma unroll
    for (int ni = 0; ni < 4; ++ni) bc[ni] = bias[n0 + wc * 64 + ni * 16 + c16];

    #pragma unroll
    for (int mi = 0; mi < 4; ++mi) {
        #pragma unroll
        for (int ni = 0; ni < 4; ++ni) {
            const int col = n0 + wc * 64 + ni * 16 + c16;
            #pragma unroll
            for (int r = 0; r < 4; ++r) {
                const int row = m0 + wr * 64 + mi * 16 + g * 4 + r;
                const float v = (acc[mi][ni][r] + bc[ni]) * oscale;
                if constexpr (sizeof(TC) == 4) {
                    C[(size_t)row * D_MODEL + col] = v;
                } else {
                    C[(size_t)row * D_MODEL + col] = f2bf(v);
                }
            }
        }
    }
}

__global__ __launch_bounds__(256) void gemm_qkv(
    const u16* __restrict__ A,
    const u16* __restrict__ BTq, const u16* __restrict__ BTk, const u16* __restrict__ BTv,
    const float* __restrict__ bq, const float* __restrict__ bk, const float* __restrict__ bv,
    u16* __restrict__ Cq, u16* __restrict__ Ck, u16* __restrict__ Cv)
{
    __shared__ u16 Al[128 * 64];
    __shared__ u16 Bl[128 * 64];
    const u16* BT; const float* bias; u16* C; float sc;
    switch (blockIdx.z) {
        case 0:  BT = BTq; bias = bq; C = Cq; sc = Q_SCALE; break;
        case 1:  BT = BTk; bias = bk; C = Ck; sc = 1.f; break;
        default: BT = BTv; bias = bv; C = Cv; sc = 1.f; break;
    }
    gemm_body<u16>(A, BT, bias, C, Al, Bl, sc);
}

__global__ __launch_bounds__(256) void gemm_out(
    const u16* __restrict__ A, const u16* __restrict__ BT,
    const float* __restrict__ bias, float* __restrict__ C)
{
    __shared__ u16 Al[128 * 64];
    __shared__ u16 Bl[128 * 64];
    gemm_body<float>(A, BT, bias, C, Al, Bl, 1.f);
}

// ---------------- V transpose: Vb[b][j][h*64+d] -> VT[bh][d][j] ----------------
__global__ __launch_bounds__(256) void transpose_v(
    const u16* __restrict__ Vb, u16* __restrict__ VT)
{
    __shared__ u16 T[64 * 65];
    const int i  = blockIdx.x;
    const int bh = i >> 5, jt = i & 31;
    const int b  = bh >> 4, h = bh & 15;
    const int j0 = jt * 64, hd = h * 64;
    const int tid = threadIdx.x;

    #pragma unroll
    for (int it = 0; it < 2; ++it) {
        int seg = it * 256 + tid;
        int jr = seg >> 3, d0 = (seg & 7) * 8;
        bf16x8 v = *reinterpret_cast<const bf16x8*>(
            Vb + ((size_t)(b * S_LEN + j0 + jr)) * D_MODEL + hd + d0);
        #pragma unroll
        for (int e = 0; e < 8; ++e) T[jr * 65 + d0 + e] = (u16)v[e];
    }
    __syncthreads();
    #pragma unroll
    for (int it = 0; it < 2; ++it) {
        int seg = it * 256 + tid;
        int d = seg >> 3, uj = (seg & 7) * 8;
        bf16x8 o;
        #pragma unroll
        for (int e = 0; e < 8; ++e) o[e] = (short)T[(uj + e) * 65 + d];
        *reinterpret_cast<bf16x8*>(
            VT + ((size_t)bh * 64 + d) * S_LEN + j0 + uj) = o;
    }
}

// ---------------- MFMA flash attention v4: barrier-free, K/V direct from global ----------------
// 2048 blocks x 256 threads (4 waves). Block i: xcd=i&7, bh=(i&7)*8+((i>>3)&7),
// qt = 31-(i>>6) (LPT). Wave w owns 16 q-rows; K/V fragments straight from global
// (L1-shared in block, L2 per-XCD), no K/V LDS, no __syncthreads.
// P goes through a per-wave LDS bounce; sched_barrier(0x7F) pins the DS write->read
// ->next-write program order (everything EXCEPT DS ops may cross) so the compiler
// cannot reorder the aliasing uint2-writes vs bf16x8-reads across iterations.
// Numerics = round-6 passing path: defer-max online softmax, f32 row-partial l.
__global__ __launch_bounds__(256, 4) void flash_attn(
    const u16* __restrict__ Qb, const u16* __restrict__ Kb,
    const u16* __restrict__ VT, u16* __restrict__ AO)
{
    __shared__ u16 P_lds[4 * 16 * 64];   // per-wave P bounce, XOR-swizzled

    const int i  = blockIdx.x;
    const int bh = (i & 7) * 8 + ((i >> 3) & 7);
    const int qt = 31 - (i >> 6);
    const int b  = bh >> 4, h = bh & 15, hd = h * 64;

    const int tid = threadIdx.x;
    const int w = tid >> 6, lane = tid & 63;
    const int g = lane >> 4, c16 = lane & 15;
    const int q0 = qt * 64 + w * 16;

    const size_t kbase  = (size_t)b * S_LEN * D_MODEL + hd;
    const size_t vtbase = (size_t)bh * 64 * S_LEN;
    u16* Pw = &P_lds[w * 1024];

    const f32x4 ZERO = {0.f, 0.f, 0.f, 0.f};
    const f32x4 NEGI = {-1e30f, -1e30f, -1e30f, -1e30f};

    // Q fragments (registers for the whole kernel)
    const size_t qrow = ((size_t)b * S_LEN + q0 + c16) * D_MODEL + hd;
    const bf16x8 qf0 = *reinterpret_cast<const bf16x8*>(Qb + qrow + g * 8);
    const bf16x8 qf1 = *reinterpret_cast<const bf16x8*>(Qb + qrow + 32 + g * 8);

    f32x4 acc[4];
    #pragma unroll
    for (int dt = 0; dt < 4; ++dt) acc[dt] = ZERO;
    float m = -1e30f, lp = 0.f;          // per-lane: row q=c16; lp = partial l over lane's j-cols

    for (int jt = 0; jt <= qt; ++jt) {
        const int j0 = jt * 64;
        const bool dtile = (jt == qt);

        // ---- K fragments direct from global: 16 rows x 64B each ----
        bf16x8 kf0[4], kf1[4];
        #pragma unroll
        for (int kt = 0; kt < 4; ++kt) {
            if (dtile && kt > w) continue;
            const u16* kp = Kb + kbase + (size_t)(j0 + kt * 16 + c16) * D_MODEL + g * 8;
            kf0[kt] = *reinterpret_cast<const bf16x8*>(kp);
            kf1[kt] = *reinterpret_cast<const bf16x8*>(kp + 32);
        }

        // ---- QK^T swapped: st[kt][r] = S[q=c16][j = j0 + kt*16 + g*4 + r] (log2 domain) ----
        f32x4 st[4];
        #pragma unroll
        for (int kt = 0; kt < 4; ++kt) {
            if (dtile && kt > w) { st[kt] = NEGI; continue; }
            f32x4 t = MFMA16(kf0[kt], qf0, ZERO, 0, 0, 0);
            t = MFMA16(kf1[kt], qf1, t, 0, 0, 0);
            if (dtile && kt == w) {
                #pragma unroll
                for (int r = 0; r < 4; ++r)
                    if (g * 4 + r > c16) t[r] = -1e30f;
            }
            st[kt] = t;
        }

        // ---- in-lane row max + 2 shfl ----
        float mx = st[0][0];
        #pragma unroll
        for (int kt = 0; kt < 4; ++kt)
            #pragma unroll
            for (int r = 0; r < 4; ++r) mx = fmaxf(mx, st[kt][r]);
        mx = fmaxf(mx, __shfl_xor(mx, 16));
        mx = fmaxf(mx, __shfl_xor(mx, 32));

        // ---- defer-max rescale (rare) ----
        if (__any(mx > m + 11.5f)) {
            const float mn = fmaxf(m, mx);
            const float co = __builtin_amdgcn_exp2f(m - mn);
            lp *= co;
            m = mn;
            float cor[4];
            #pragma unroll
            for (int r = 0; r < 4; ++r) cor[r] = __shfl(co, g * 4 + r);
            #pragma unroll
            for (int dt = 0; dt < 4; ++dt)
                #pragma unroll
                for (int r = 0; r < 4; ++r) acc[dt][r] *= cor[r];
        }

        // ---- p = exp2(s - m); l partial in-lane; P -> LDS via cvt_pk + b64 ----
        float tsum = 0.f;
        #pragma unroll
        for (int kt = 0; kt < 4; ++kt) {
            const float p0 = __builtin_amdgcn_exp2f(st[kt][0] - m);
            const float p1 = __builtin_amdgcn_exp2f(st[kt][1] - m);
            const float p2 = __builtin_amdgcn_exp2f(st[kt][2] - m);
            const float p3 = __builtin_amdgcn_exp2f(st[kt][3] - m);
            tsum += (p0 + p1) + (p2 + p3);
            uint2 pw;
            pw.x = cvtpk(p0, p1);
            pw.y = cvtpk(p2, p3);
            const int u = kt * 2 + (g >> 1);
            *reinterpret_cast<uint2*>(
                &Pw[c16 * 64 + ((u ^ (c16 & 7)) << 3) + (g & 1) * 4]) = pw;
        }
        lp += tsum;

        // DS-ordering fence: P writes above may not swap with P reads below.
        __builtin_amdgcn_sched_barrier(0x7F);

        // ---- PV: acc[dt] += P[16x32] * V[32x16] ----
        #pragma unroll
        for (int c32 = 0; c32 < 2; ++c32) {
            if (dtile && c32 == 1 && w < 2) continue;
            const bf16x8 pf = *reinterpret_cast<const bf16x8*>(
                &Pw[c16 * 64 + (((c32 * 4 + g) ^ (c16 & 7)) << 3)]);
            #pragma unroll
            for (int dt = 0; dt < 4; ++dt) {
                const bf16x8 vf = *reinterpret_cast<const bf16x8*>(
                    VT + vtbase + (size_t)(dt * 16 + c16) * S_LEN + j0 + c32 * 32 + g * 8);
                acc[dt] = MFMA16(pf, vf, acc[dt], 0, 0, 0);
            }
        }

        // DS-ordering fence: this tile's P reads may not swap with next tile's writes.
        __builtin_amdgcn_sched_barrier(0x7F);
    }

    // ---- epilogue: cross-lane l reduce (deferred), write O ----
    float lt = lp + __shfl_xor(lp, 16);
    lt += __shfl_xor(lt, 32);
    const float inv = 1.f / lt;
    float invr[4];
    #pragma unroll
    for (int r = 0; r < 4; ++r) invr[r] = __shfl(inv, g * 4 + r);

    #pragma unroll
    for (int dt = 0; dt < 4; ++dt) {
        #pragma unroll
        for (int r = 0; r < 4; ++r) {
            const size_t orow =
                ((size_t)b * S_LEN + q0 + g * 4 + r) * D_MODEL + hd + dt * 16 + c16;
            AO[orow] = f2bf(acc[dt][r] * invr[r]);
        }
    }
}

extern "C" void kernel_launch(void* const* d_in, const int* in_sizes, int n_in,
                              void* d_out, int out_size, void* d_ws, size_t ws_size,
                              hipStream_t stream) {
    const float* x  = (const float*)d_in[0];
    // d_in[1] = causal mask: applied structurally — not read.
    const float* Wq = (const float*)d_in[2];
    const float* bq = (const float*)d_in[3];
    const float* Wk = (const float*)d_in[4];
    const float* bk = (const float*)d_in[5];
    const float* Wv = (const float*)d_in[6];
    const float* bv = (const float*)d_in[7];
    const float* Wo = (const float*)d_in[8];
    const float* bo = (const float*)d_in[9];
    float* out = (float*)d_out;

    const int M = BATCH * S_LEN;              // 8192
    const size_t tsz = (size_t)M * D_MODEL;
    const size_t wsz = (size_t)D_MODEL * D_MODEL;

    u16* xb  = (u16*)d_ws;
    u16* Qb  = xb + tsz;
    u16* Kb  = Qb + tsz;
    u16* Vb  = Kb + tsz;
    u16* VT  = Vb + tsz;
    u16* WTq = VT + tsz;
    u16* WTk = WTq + wsz;
    u16* WTv = WTk + wsz;
    u16* WTo = WTv + wsz;
    u16* AO  = Vb;             // Vb dead after transpose_v

    convert_x<<<(int)(tsz / (256 * 8)), 256, 0, stream>>>(x, xb);
    transpose_w<<<dim3(16, 16, 4), 256, 0, stream>>>(
        Wq, Wk, Wv, Wo, WTq, WTk, WTv, WTo);

    gemm_qkv<<<dim3(8, 64, 3), 256, 0, stream>>>(
        xb, WTq, WTk, WTv, bq, bk, bv, Qb, Kb, Vb);

    transpose_v<<<2048, 256, 0, stream>>>(Vb, VT);
    flash_attn<<<2048, 256, 0, stream>>>(Qb, Kb, VT, AO);

    gemm_out<<<dim3(8, 64), 256, 0, stream>>>(AO, WTo, bo, out);
}

// Round 9
// 202.136 us; speedup vs baseline: 1.7329x; 1.7329x over previous
//
#include <hip/hip_runtime.h>
#include <hip/hip_bf16.h>

#define D_MODEL 1024
#define NUM_HEADS 16
#define D_K 64
#define S_LEN 2048
#define BATCH 4

typedef unsigned short u16;
typedef __attribute__((ext_vector_type(8))) short bf16x8;
typedef __attribute__((ext_vector_type(4))) float f32x4;

#define MFMA16 __builtin_amdgcn_mfma_f32_16x16x32_bf16

// fold attn scale + ln2 conversion into the Q projection: 0.125 * log2(e)
#define Q_SCALE 0.18033688011112042f

__device__ __forceinline__ float bf2f(u16 u) {
    union { unsigned int i; float f; } v; v.i = ((unsigned int)u) << 16; return v.f;
}
__device__ __forceinline__ u16 f2bf(float f) {
    union { unsigned int i; float f; } v; v.f = f;
    unsigned int x = v.i;
    return (u16)((x + 0x7FFFu + ((x >> 16) & 1u)) >> 16); // round-nearest-even
}
// packed f32x2 -> bf16x2 (RNE), single HW op
__device__ __forceinline__ unsigned int cvtpk(float lo, float hi) {
    unsigned int r;
    asm("v_cvt_pk_bf16_f32 %0, %1, %2" : "=v"(r) : "v"(lo), "v"(hi));
    return r;
}

__device__ __forceinline__ void gload16(const u16* g, u16* l) {
    __builtin_amdgcn_global_load_lds(
        (const __attribute__((address_space(1))) unsigned int*)g,
        (__attribute__((address_space(3))) unsigned int*)l, 16, 0, 0);
}

// ---------------- prep: x fp32 -> bf16 ----------------
__global__ __launch_bounds__(256) void convert_x(
    const float* __restrict__ x, u16* __restrict__ xb)
{
    const size_t i = ((size_t)blockIdx.x * 256 + threadIdx.x) * 8;
    float4 a = *reinterpret_cast<const float4*>(x + i);
    float4 b = *reinterpret_cast<const float4*>(x + i + 4);
    bf16x8 o;
    o[0] = (short)f2bf(a.x); o[1] = (short)f2bf(a.y);
    o[2] = (short)f2bf(a.z); o[3] = (short)f2bf(a.w);
    o[4] = (short)f2bf(b.x); o[5] = (short)f2bf(b.y);
    o[6] = (short)f2bf(b.z); o[7] = (short)f2bf(b.w);
    *reinterpret_cast<bf16x8*>(xb + i) = o;
}

// ---------------- prep: W[k][n] fp32 -> WT[n][k] bf16 (4 matrices) ----------------
__global__ __launch_bounds__(256) void transpose_w(
    const float* __restrict__ W0, const float* __restrict__ W1,
    const float* __restrict__ W2, const float* __restrict__ W3,
    u16* __restrict__ T0, u16* __restrict__ T1,
    u16* __restrict__ T2, u16* __restrict__ T3)
{
    const float* W; u16* T;
    switch (blockIdx.z & 3) {
        case 0:  W = W0; T = T0; break;
        case 1:  W = W1; T = T1; break;
        case 2:  W = W2; T = T2; break;
        default: W = W3; T = T3; break;
    }
    __shared__ u16 S[64][72];
    const int tid = threadIdx.x;
    const int k0 = blockIdx.y * 64, n0 = blockIdx.x * 64;

    const int k = tid >> 2, nb = (tid & 3) * 16;
    #pragma unroll
    for (int c = 0; c < 4; ++c) {
        float4 v = *reinterpret_cast<const float4*>(
            W + (size_t)(k0 + k) * D_MODEL + n0 + nb + c * 4);
        S[nb + c * 4 + 0][k] = f2bf(v.x);
        S[nb + c * 4 + 1][k] = f2bf(v.y);
        S[nb + c * 4 + 2][k] = f2bf(v.z);
        S[nb + c * 4 + 3][k] = f2bf(v.w);
    }
    __syncthreads();
    const int n = tid >> 2, kb = (tid & 3) * 16;
    #pragma unroll
    for (int c = 0; c < 2; ++c) {
        bf16x8 o;
        #pragma unroll
        for (int e = 0; e < 8; ++e) o[e] = (short)S[n][kb + c * 8 + e];
        *reinterpret_cast<bf16x8*>(T + (size_t)(n0 + n) * D_MODEL + k0 + kb + c * 8) = o;
    }
}

// ---------------- MFMA GEMM: C = A[8192,1024] @ BT[1024,1024]^T + bias, then *oscale ----------------
template <typename TC>
__device__ __forceinline__ void gemm_body(
    const u16* __restrict__ A, const u16* __restrict__ BT,
    const float* __restrict__ bias, TC* __restrict__ C,
    u16* Al, u16* Bl, float oscale)
{
    const int tid = threadIdx.x;
    const int w = tid >> 6, lane = tid & 63;
    const int g = lane >> 4, c16 = lane & 15;
    const int wr = w >> 1, wc = w & 1;
    const int m0 = blockIdx.y * 128, n0 = blockIdx.x * 128;

    int rS[4], uS[4];
    #pragma unroll
    for (int i = 0; i < 4; ++i) {
        const int p = i * 256 + tid;
        rS[i] = p >> 3;
        uS[i] = ((p & 7) ^ (rS[i] & 7)) * 8;
    }

    f32x4 acc[4][4];
    #pragma unroll
    for (int mi = 0; mi < 4; ++mi)
        #pragma unroll
        for (int ni = 0; ni < 4; ++ni) acc[mi][ni] = (f32x4){0.f, 0.f, 0.f, 0.f};

    for (int k0 = 0; k0 < D_MODEL; k0 += 64) {
        #pragma unroll
        for (int i = 0; i < 4; ++i) {
            gload16(A + (size_t)(m0 + rS[i]) * D_MODEL + k0 + uS[i],
                    Al + (size_t)(i * 256 + w * 64) * 8);
            gload16(BT + (size_t)(n0 + rS[i]) * D_MODEL + k0 + uS[i],
                    Bl + (size_t)(i * 256 + w * 64) * 8);
        }
        __syncthreads();

        #pragma unroll
        for (int s = 0; s < 2; ++s) {
            bf16x8 af[4], bfr[4];
            #pragma unroll
            for (int mi = 0; mi < 4; ++mi) {
                const int r = wr * 64 + mi * 16 + c16;
                af[mi] = *reinterpret_cast<const bf16x8*>(
                    &Al[((r << 3) + ((s * 4 + g) ^ (r & 7))) * 8]);
            }
            #pragma unroll
            for (int ni = 0; ni < 4; ++ni) {
                const int r = wc * 64 + ni * 16 + c16;
                bfr[ni] = *reinterpret_cast<const bf16x8*>(
                    &Bl[((r << 3) + ((s * 4 + g) ^ (r & 7))) * 8]);
            }
            #pragma unroll
            for (int mi = 0; mi < 4; ++mi)
                #pragma unroll
                for (int ni = 0; ni < 4; ++ni)
                    acc[mi][ni] = MFMA16(af[mi], bfr[ni], acc[mi][ni], 0, 0, 0);
        }
        __syncthreads();
    }

    float bc[4];
    #pragma unroll
    for (int ni = 0; ni < 4; ++ni) bc[ni] = bias[n0 + wc * 64 + ni * 16 + c16];

    #pragma unroll
    for (int mi = 0; mi < 4; ++mi) {
        #pragma unroll
        for (int ni = 0; ni < 4; ++ni) {
            const int col = n0 + wc * 64 + ni * 16 + c16;
            #pragma unroll
            for (int r = 0; r < 4; ++r) {
                const int row = m0 + wr * 64 + mi * 16 + g * 4 + r;
                const float v = (acc[mi][ni][r] + bc[ni]) * oscale;
                if constexpr (sizeof(TC) == 4) {
                    C[(size_t)row * D_MODEL + col] = v;
                } else {
                    C[(size_t)row * D_MODEL + col] = f2bf(v);
                }
            }
        }
    }
}

__global__ __launch_bounds__(256) void gemm_qkv(
    const u16* __restrict__ A,
    const u16* __restrict__ BTq, const u16* __restrict__ BTk, const u16* __restrict__ BTv,
    const float* __restrict__ bq, const float* __restrict__ bk, const float* __restrict__ bv,
    u16* __restrict__ Cq, u16* __restrict__ Ck, u16* __restrict__ Cv)
{
    __shared__ u16 Al[128 * 64];
    __shared__ u16 Bl[128 * 64];
    const u16* BT; const float* bias; u16* C; float sc;
    switch (blockIdx.z) {
        case 0:  BT = BTq; bias = bq; C = Cq; sc = Q_SCALE; break;
        case 1:  BT = BTk; bias = bk; C = Ck; sc = 1.f; break;
        default: BT = BTv; bias = bv; C = Cv; sc = 1.f; break;
    }
    gemm_body<u16>(A, BT, bias, C, Al, Bl, sc);
}

__global__ __launch_bounds__(256) void gemm_out(
    const u16* __restrict__ A, const u16* __restrict__ BT,
    const float* __restrict__ bias, float* __restrict__ C)
{
    __shared__ u16 Al[128 * 64];
    __shared__ u16 Bl[128 * 64];
    gemm_body<float>(A, BT, bias, C, Al, Bl, 1.f);
}

// ---------------- V transpose: Vb[b][j][h*64+d] -> VT[bh][d][j] ----------------
__global__ __launch_bounds__(256) void transpose_v(
    const u16* __restrict__ Vb, u16* __restrict__ VT)
{
    __shared__ u16 T[64 * 65];
    const int i  = blockIdx.x;
    const int bh = i >> 5, jt = i & 31;
    const int b  = bh >> 4, h = bh & 15;
    const int j0 = jt * 64, hd = h * 64;
    const int tid = threadIdx.x;

    #pragma unroll
    for (int it = 0; it < 2; ++it) {
        int seg = it * 256 + tid;
        int jr = seg >> 3, d0 = (seg & 7) * 8;
        bf16x8 v = *reinterpret_cast<const bf16x8*>(
            Vb + ((size_t)(b * S_LEN + j0 + jr)) * D_MODEL + hd + d0);
        #pragma unroll
        for (int e = 0; e < 8; ++e) T[jr * 65 + d0 + e] = (u16)v[e];
    }
    __syncthreads();
    #pragma unroll
    for (int it = 0; it < 2; ++it) {
        int seg = it * 256 + tid;
        int d = seg >> 3, uj = (seg & 7) * 8;
        bf16x8 o;
        #pragma unroll
        for (int e = 0; e < 8; ++e) o[e] = (short)T[(uj + e) * 65 + d];
        *reinterpret_cast<bf16x8*>(
            VT + ((size_t)bh * 64 + d) * S_LEN + j0 + uj) = o;
    }
}

// ---------------- MFMA flash attention v5: double-buffered prefetch (T3 2-phase) ----------------
// 1024 blocks x 512 threads (8 waves). Block i: xcd=i&7, bh=(i&7)*8+((i>>3)&7), p=i>>6
// (LPT: p ascending => cost 32-p descending). Waves 0-3 own q-tile p, waves 4-7 own 31-p;
// one K/V stage per jt serves both. Prefetch of tile jt+1 issued BEFORE computing jt:
// the global_load_lds DMAs fly under the MFMA/softmax work and the single end-of-iter
// barrier (compiler-drained vmcnt) finds them complete. Numerics = round-6 passing path.
__global__ __launch_bounds__(512, 6) void flash_attn(
    const u16* __restrict__ Qb, const u16* __restrict__ Kb,
    const u16* __restrict__ VT, u16* __restrict__ AO)
{
    __shared__ u16 K_lds[2][4096];       // [buf][key j][d], XOR-swizzled 16B units
    __shared__ u16 V_lds[2][4096];       // [buf][d][key j], XOR-swizzled
    __shared__ u16 P_lds[8 * 1024];      // per-wave [q][j], XOR-swizzled

    const int i  = blockIdx.x;
    const int bh = (i & 7) * 8 + ((i >> 3) & 7);
    const int p  = i >> 6;               // 0..15
    const int b  = bh >> 4, h = bh & 15, hd = h * 64;

    const int tid = threadIdx.x;
    const int w = tid >> 6, lane = tid & 63;
    const int wq = w & 3;
    const int g = lane >> 4, c16 = lane & 15;

    const int qt = (w < 4) ? p : (31 - p);
    const int q0 = qt * 64 + wq * 16;

    const size_t kbase  = (size_t)b * S_LEN * D_MODEL + hd;
    const size_t vtbase = (size_t)bh * 64 * S_LEN;
    u16* Pw = &P_lds[w * 1024];

    const f32x4 ZERO = {0.f, 0.f, 0.f, 0.f};
    const f32x4 NEGI = {-1e30f, -1e30f, -1e30f, -1e30f};

    // staging: each of 512 threads stages one 16B unit of K and one of V
    const int rK = tid >> 3;
    const int uK = ((tid & 7) ^ (rK & 7)) * 8;

    const size_t qrow = ((size_t)b * S_LEN + q0 + c16) * D_MODEL + hd;
    const bf16x8 qf0 = *reinterpret_cast<const bf16x8*>(Qb + qrow + g * 8);
    const bf16x8 qf1 = *reinterpret_cast<const bf16x8*>(Qb + qrow + 32 + g * 8);

    f32x4 acc[4];
    #pragma unroll
    for (int dt = 0; dt < 4; ++dt) acc[dt] = ZERO;
    float m = -1e30f, lp = 0.f;          // per-lane: row q=c16; lp = partial l over lane's j-cols

    const int nt = 32 - p;               // iterations (long group's tile count)

    // prologue: stage tile 0 into buf 0
    gload16(Kb + kbase + (size_t)rK * D_MODEL + uK, &K_lds[0][tid * 8]);
    gload16(VT + vtbase + (size_t)rK * S_LEN + uK,  &V_lds[0][tid * 8]);
    __syncthreads();

    int cur = 0;
    for (int jt = 0; jt < nt; ++jt) {
        // ---- prefetch next tile into the other buffer (overlaps with compute below) ----
        if (jt + 1 < nt) {
            const int j0n = (jt + 1) * 64;
            gload16(Kb + kbase + (size_t)(j0n + rK) * D_MODEL + uK, &K_lds[cur ^ 1][tid * 8]);
            gload16(VT + vtbase + (size_t)rK * S_LEN + j0n + uK,    &V_lds[cur ^ 1][tid * 8]);
        }

        if (jt <= qt) {
            const bool dtile = (jt == qt);
            const u16* kl = K_lds[cur];
            const u16* vl = V_lds[cur];

            // ---- QK^T swapped: st[kt][r] = S[q=c16][j = kt*16 + g*4 + r] (log2 domain) ----
            f32x4 st[4];
            __builtin_amdgcn_s_setprio(1);
            #pragma unroll
            for (int kt = 0; kt < 4; ++kt) {
                if (dtile && kt > wq) { st[kt] = NEGI; continue; }
                const int row = kt * 16 + c16;
                const bf16x8 kf0 = *reinterpret_cast<const bf16x8*>(
                    &kl[row * 64 + ((g ^ (row & 7)) << 3)]);
                const bf16x8 kf1 = *reinterpret_cast<const bf16x8*>(
                    &kl[row * 64 + (((4 + g) ^ (row & 7)) << 3)]);
                f32x4 t = MFMA16(kf0, qf0, ZERO, 0, 0, 0);
                t = MFMA16(kf1, qf1, t, 0, 0, 0);
                if (dtile && kt == wq) {
                    #pragma unroll
                    for (int r = 0; r < 4; ++r)
                        if (g * 4 + r > c16) t[r] = -1e30f;
                }
                st[kt] = t;
            }
            __builtin_amdgcn_s_setprio(0);

            // ---- in-lane row max + 2 shfl ----
            float mx = st[0][0];
            #pragma unroll
            for (int kt = 0; kt < 4; ++kt)
                #pragma unroll
                for (int r = 0; r < 4; ++r) mx = fmaxf(mx, st[kt][r]);
            mx = fmaxf(mx, __shfl_xor(mx, 16));
            mx = fmaxf(mx, __shfl_xor(mx, 32));

            // ---- defer-max rescale (rare) ----
            if (__any(mx > m + 11.5f)) {
                const float mn = fmaxf(m, mx);
                const float co = __builtin_amdgcn_exp2f(m - mn);
                lp *= co;
                m = mn;
                float cor[4];
                #pragma unroll
                for (int r = 0; r < 4; ++r) cor[r] = __shfl(co, g * 4 + r);
                #pragma unroll
                for (int dt = 0; dt < 4; ++dt)
                    #pragma unroll
                    for (int r = 0; r < 4; ++r) acc[dt][r] *= cor[r];
            }

            // ---- p = exp2(s - m); l partial in-lane; P -> LDS via cvt_pk + b64 ----
            float tsum = 0.f;
            #pragma unroll
            for (int kt = 0; kt < 4; ++kt) {
                const float p0 = __builtin_amdgcn_exp2f(st[kt][0] - m);
                const float p1 = __builtin_amdgcn_exp2f(st[kt][1] - m);
                const float p2 = __builtin_amdgcn_exp2f(st[kt][2] - m);
                const float p3 = __builtin_amdgcn_exp2f(st[kt][3] - m);
                tsum += (p0 + p1) + (p2 + p3);
                uint2 pw;
                pw.x = cvtpk(p0, p1);
                pw.y = cvtpk(p2, p3);
                const int u = kt * 2 + (g >> 1);
                *reinterpret_cast<uint2*>(
                    &Pw[c16 * 64 + ((u ^ (c16 & 7)) << 3) + (g & 1) * 4]) = pw;
            }
            lp += tsum;

            // DS-ordering fence: P writes above may not swap with P reads below.
            __builtin_amdgcn_sched_barrier(0x7F);

            // ---- PV: acc[dt] += P[16x32] * V[32x16] ----
            __builtin_amdgcn_s_setprio(1);
            #pragma unroll
            for (int c32 = 0; c32 < 2; ++c32) {
                if (dtile && c32 == 1 && wq < 2) continue;
                const bf16x8 pf = *reinterpret_cast<const bf16x8*>(
                    &Pw[c16 * 64 + (((c32 * 4 + g) ^ (c16 & 7)) << 3)]);
                #pragma unroll
                for (int dt = 0; dt < 4; ++dt) {
                    const int vrow = dt * 16 + c16;
                    const bf16x8 vf = *reinterpret_cast<const bf16x8*>(
                        &vl[vrow * 64 + (((c32 * 4 + g) ^ (vrow & 7)) << 3)]);
                    acc[dt] = MFMA16(pf, vf, acc[dt], 0, 0, 0);
                }
            }
            __builtin_amdgcn_s_setprio(0);

            // DS-ordering fence: this tile's P reads may not swap with next tile's writes.
            __builtin_amdgcn_sched_barrier(0x7F);
        }

        __syncthreads();                 // prefetch DMAs drained + all waves done with cur
        cur ^= 1;
    }

    // ---- epilogue: cross-lane l reduce (deferred), write O ----
    float lt = lp + __shfl_xor(lp, 16);
    lt += __shfl_xor(lt, 32);
    const float inv = 1.f / lt;
    float invr[4];
    #pragma unroll
    for (int r = 0; r < 4; ++r) invr[r] = __shfl(inv, g * 4 + r);

    #pragma unroll
    for (int dt = 0; dt < 4; ++dt) {
        #pragma unroll
        for (int r = 0; r < 4; ++r) {
            const size_t orow =
                ((size_t)b * S_LEN + q0 + g * 4 + r) * D_MODEL + hd + dt * 16 + c16;
            AO[orow] = f2bf(acc[dt][r] * invr[r]);
        }
    }
}

extern "C" void kernel_launch(void* const* d_in, const int* in_sizes, int n_in,
                              void* d_out, int out_size, void* d_ws, size_t ws_size,
                              hipStream_t stream) {
    const float* x  = (const float*)d_in[0];
    // d_in[1] = causal mask: applied structurally — not read.
    const float* Wq = (const float*)d_in[2];
    const float* bq = (const float*)d_in[3];
    const float* Wk = (const float*)d_in[4];
    const float* bk = (const float*)d_in[5];
    const float* Wv = (const float*)d_in[6];
    const float* bv = (const float*)d_in[7];
    const float* Wo = (const float*)d_in[8];
    const float* bo = (const float*)d_in[9];
    float* out = (float*)d_out;

    const int M = BATCH * S_LEN;              // 8192
    const size_t tsz = (size_t)M * D_MODEL;
    const size_t wsz = (size_t)D_MODEL * D_MODEL;

    u16* xb  = (u16*)d_ws;
    u16* Qb  = xb + tsz;
    u16* Kb  = Qb + tsz;
    u16* Vb  = Kb + tsz;
    u16* VT  = Vb + tsz;
    u16* WTq = VT + tsz;
    u16* WTk = WTq + wsz;
    u16* WTv = WTk + wsz;
    u16* WTo = WTv + wsz;
    u16* AO  = Vb;             // Vb dead after transpose_v

    convert_x<<<(int)(tsz / (256 * 8)), 256, 0, stream>>>(x, xb);
    transpose_w<<<dim3(16, 16, 4), 256, 0, stream>>>(
        Wq, Wk, Wv, Wo, WTq, WTk, WTv, WTo);

    gemm_qkv<<<dim3(8, 64, 3), 256, 0, stream>>>(
        xb, WTq, WTk, WTv, bq, bk, bv, Qb, Kb, Vb);

    transpose_v<<<2048, 256, 0, stream>>>(Vb, VT);
    flash_attn<<<1024, 512, 0, stream>>>(Qb, Kb, VT, AO);

    gemm_out<<<dim3(8, 64), 256, 0, stream>>>(AO, WTo, bo, out);
}

// Round 12
// 196.212 us; speedup vs baseline: 1.7852x; 1.0302x over previous
//
#include <hip/hip_runtime.h>
#include <hip/hip_bf16.h>

#define D_MODEL 1024
#define NUM_HEADS 16
#define D_K 64
#define S_LEN 2048
#define BATCH 4

typedef unsigned short u16;
typedef __attribute__((ext_vector_type(8))) short bf16x8;
typedef __attribute__((ext_vector_type(4))) float f32x4;

#define MFMA16 __builtin_amdgcn_mfma_f32_16x16x32_bf16

// fold attn scale + ln2 conversion into the Q projection: 0.125 * log2(e)
#define Q_SCALE 0.18033688011112042f

__device__ __forceinline__ float bf2f(u16 u) {
    union { unsigned int i; float f; } v; v.i = ((unsigned int)u) << 16; return v.f;
}
__device__ __forceinline__ u16 f2bf(float f) {
    union { unsigned int i; float f; } v; v.f = f;
    unsigned int x = v.i;
    return (u16)((x + 0x7FFFu + ((x >> 16) & 1u)) >> 16); // round-nearest-even
}
// packed f32x2 -> bf16x2 (RNE), single HW op
__device__ __forceinline__ unsigned int cvtpk(float lo, float hi) {
    unsigned int r;
    asm("v_cvt_pk_bf16_f32 %0, %1, %2" : "=v"(r) : "v"(lo), "v"(hi));
    return r;
}

__device__ __forceinline__ void gload16(const u16* g, u16* l) {
    __builtin_amdgcn_global_load_lds(
        (const __attribute__((address_space(1))) unsigned int*)g,
        (__attribute__((address_space(3))) unsigned int*)l, 16, 0, 0);
}

// ---------------- prep: x fp32 -> bf16 ----------------
__global__ __launch_bounds__(256) void convert_x(
    const float* __restrict__ x, u16* __restrict__ xb)
{
    const size_t i = ((size_t)blockIdx.x * 256 + threadIdx.x) * 8;
    float4 a = *reinterpret_cast<const float4*>(x + i);
    float4 b = *reinterpret_cast<const float4*>(x + i + 4);
    bf16x8 o;
    o[0] = (short)f2bf(a.x); o[1] = (short)f2bf(a.y);
    o[2] = (short)f2bf(a.z); o[3] = (short)f2bf(a.w);
    o[4] = (short)f2bf(b.x); o[5] = (short)f2bf(b.y);
    o[6] = (short)f2bf(b.z); o[7] = (short)f2bf(b.w);
    *reinterpret_cast<bf16x8*>(xb + i) = o;
}

// ---------------- prep: W[k][n] fp32 -> WT[n][k] bf16 (4 matrices) ----------------
__global__ __launch_bounds__(256) void transpose_w(
    const float* __restrict__ W0, const float* __restrict__ W1,
    const float* __restrict__ W2, const float* __restrict__ W3,
    u16* __restrict__ T0, u16* __restrict__ T1,
    u16* __restrict__ T2, u16* __restrict__ T3)
{
    const float* W; u16* T;
    switch (blockIdx.z & 3) {
        case 0:  W = W0; T = T0; break;
        case 1:  W = W1; T = T1; break;
        case 2:  W = W2; T = T2; break;
        default: W = W3; T = T3; break;
    }
    __shared__ u16 S[64][72];
    const int tid = threadIdx.x;
    const int k0 = blockIdx.y * 64, n0 = blockIdx.x * 64;

    const int k = tid >> 2, nb = (tid & 3) * 16;
    #pragma unroll
    for (int c = 0; c < 4; ++c) {
        float4 v = *reinterpret_cast<const float4*>(
            W + (size_t)(k0 + k) * D_MODEL + n0 + nb + c * 4);
        S[nb + c * 4 + 0][k] = f2bf(v.x);
        S[nb + c * 4 + 1][k] = f2bf(v.y);
        S[nb + c * 4 + 2][k] = f2bf(v.z);
        S[nb + c * 4 + 3][k] = f2bf(v.w);
    }
    __syncthreads();
    const int n = tid >> 2, kb = (tid & 3) * 16;
    #pragma unroll
    for (int c = 0; c < 2; ++c) {
        bf16x8 o;
        #pragma unroll
        for (int e = 0; e < 8; ++e) o[e] = (short)S[n][kb + c * 8 + e];
        *reinterpret_cast<bf16x8*>(T + (size_t)(n0 + n) * D_MODEL + k0 + kb + c * 8) = o;
    }
}

// ---------------- MFMA GEMM: C = A[8192,1024] @ BT[1024,1024]^T + bias ----------------
// EPI: 0 = bf16 row-major, 1 = fp32 row-major, 2 = bf16 transposed-per-head
//      (EPI 2 writes VT[bh][d][j]: bh=(row>>11)*16+(col>>6), d=col&63, j=row&2047 —
//       r-index maps to consecutive j, so each (mi,ni) is one ushort4 store).
template <int EPI, typename TC>
__device__ __forceinline__ void gemm_body(
    const u16* __restrict__ A, const u16* __restrict__ BT,
    const float* __restrict__ bias, TC* __restrict__ C,
    u16* Al, u16* Bl, float oscale)
{
    const int tid = threadIdx.x;
    const int w = tid >> 6, lane = tid & 63;
    const int g = lane >> 4, c16 = lane & 15;
    const int wr = w >> 1, wc = w & 1;
    const int m0 = blockIdx.y * 128, n0 = blockIdx.x * 128;

    int rS[4], uS[4];
    #pragma unroll
    for (int i = 0; i < 4; ++i) {
        const int p = i * 256 + tid;
        rS[i] = p >> 3;
        uS[i] = ((p & 7) ^ (rS[i] & 7)) * 8;
    }

    f32x4 acc[4][4];
    #pragma unroll
    for (int mi = 0; mi < 4; ++mi)
        #pragma unroll
        for (int ni = 0; ni < 4; ++ni) acc[mi][ni] = (f32x4){0.f, 0.f, 0.f, 0.f};

    for (int k0 = 0; k0 < D_MODEL; k0 += 64) {
        #pragma unroll
        for (int i = 0; i < 4; ++i) {
            gload16(A + (size_t)(m0 + rS[i]) * D_MODEL + k0 + uS[i],
                    Al + (size_t)(i * 256 + w * 64) * 8);
            gload16(BT + (size_t)(n0 + rS[i]) * D_MODEL + k0 + uS[i],
                    Bl + (size_t)(i * 256 + w * 64) * 8);
        }
        __syncthreads();

        #pragma unroll
        for (int s = 0; s < 2; ++s) {
            bf16x8 af[4], bfr[4];
            #pragma unroll
            for (int mi = 0; mi < 4; ++mi) {
                const int r = wr * 64 + mi * 16 + c16;
                af[mi] = *reinterpret_cast<const bf16x8*>(
                    &Al[((r << 3) + ((s * 4 + g) ^ (r & 7))) * 8]);
            }
            #pragma unroll
            for (int ni = 0; ni < 4; ++ni) {
                const int r = wc * 64 + ni * 16 + c16;
                bfr[ni] = *reinterpret_cast<const bf16x8*>(
                    &Bl[((r << 3) + ((s * 4 + g) ^ (r & 7))) * 8]);
            }
            #pragma unroll
            for (int mi = 0; mi < 4; ++mi)
                #pragma unroll
                for (int ni = 0; ni < 4; ++ni)
                    acc[mi][ni] = MFMA16(af[mi], bfr[ni], acc[mi][ni], 0, 0, 0);
        }
        __syncthreads();
    }

    float bc[4];
    #pragma unroll
    for (int ni = 0; ni < 4; ++ni) bc[ni] = bias[n0 + wc * 64 + ni * 16 + c16];

    if constexpr (EPI == 2) {
        const int rowb = m0 + wr * 64 + g * 4;        // token row base (+mi*16, +r)
        const int bb = rowb >> 11;                    // batch (tile never crosses)
        #pragma unroll
        for (int mi = 0; mi < 4; ++mi) {
            const int row = rowb + mi * 16;
            const int jj = row & 2047;
            #pragma unroll
            for (int ni = 0; ni < 4; ++ni) {
                const int col = n0 + wc * 64 + ni * 16 + c16;
                ushort4 ov;
                ov.x = f2bf(acc[mi][ni][0] + bc[ni]);
                ov.y = f2bf(acc[mi][ni][1] + bc[ni]);
                ov.z = f2bf(acc[mi][ni][2] + bc[ni]);
                ov.w = f2bf(acc[mi][ni][3] + bc[ni]);
                *reinterpret_cast<ushort4*>(
                    &C[((size_t)(bb * 16 + (col >> 6)) * 64 + (col & 63)) * S_LEN + jj]) = ov;
            }
        }
    } else {
        #pragma unroll
        for (int mi = 0; mi < 4; ++mi) {
            #pragma unroll
            for (int ni = 0; ni < 4; ++ni) {
                const int col = n0 + wc * 64 + ni * 16 + c16;
                #pragma unroll
                for (int r = 0; r < 4; ++r) {
                    const int row = m0 + wr * 64 + mi * 16 + g * 4 + r;
                    const float v = (acc[mi][ni][r] + bc[ni]) * oscale;
                    if constexpr (EPI == 1) {
                        C[(size_t)row * D_MODEL + col] = v;
                    } else {
                        C[(size_t)row * D_MODEL + col] = f2bf(v);
                    }
                }
            }
        }
    }
}

__global__ __launch_bounds__(256) void gemm_qkv(
    const u16* __restrict__ A,
    const u16* __restrict__ BTq, const u16* __restrict__ BTk, const u16* __restrict__ BTv,
    const float* __restrict__ bq, const float* __restrict__ bk, const float* __restrict__ bv,
    u16* __restrict__ Cq, u16* __restrict__ Ck, u16* __restrict__ Cv)
{
    __shared__ u16 Al[128 * 64];
    __shared__ u16 Bl[128 * 64];
    switch (blockIdx.z) {
        case 0:  gemm_body<0, u16>(A, BTq, bq, Cq, Al, Bl, Q_SCALE); break;
        case 1:  gemm_body<0, u16>(A, BTk, bk, Ck, Al, Bl, 1.f);     break;
        default: gemm_body<2, u16>(A, BTv, bv, Cv, Al, Bl, 1.f);     break;  // -> VT
    }
}

__global__ __launch_bounds__(256) void gemm_out(
    const u16* __restrict__ A, const u16* __restrict__ BT,
    const float* __restrict__ bias, float* __restrict__ C)
{
    __shared__ u16 Al[128 * 64];
    __shared__ u16 Bl[128 * 64];
    gemm_body<1, float>(A, BT, bias, C, Al, Bl, 1.f);
}

// ---------------- MFMA flash attention v5 (byte-identical to round-9 passing kernel) ----------------
// 1024 blocks x 512 threads (8 waves). Block i: xcd=i&7, bh=(i&7)*8+((i>>3)&7), p=i>>6
// (LPT: p ascending => cost 32-p descending). Waves 0-3 own q-tile p, waves 4-7 own 31-p;
// one K/V stage per jt serves both. Prefetch of tile jt+1 issued BEFORE computing jt.
__global__ __launch_bounds__(512, 6) void flash_attn(
    const u16* __restrict__ Qb, const u16* __restrict__ Kb,
    const u16* __restrict__ VT, u16* __restrict__ AO)
{
    __shared__ u16 K_lds[2][4096];       // [buf][key j][d], XOR-swizzled 16B units
    __shared__ u16 V_lds[2][4096];       // [buf][d][key j], XOR-swizzled
    __shared__ u16 P_lds[8 * 1024];      // per-wave [q][j], XOR-swizzled

    const int i  = blockIdx.x;
    const int bh = (i & 7) * 8 + ((i >> 3) & 7);
    const int p  = i >> 6;               // 0..15
    const int b  = bh >> 4, h = bh & 15, hd = h * 64;

    const int tid = threadIdx.x;
    const int w = tid >> 6, lane = tid & 63;
    const int wq = w & 3;
    const int g = lane >> 4, c16 = lane & 15;

    const int qt = (w < 4) ? p : (31 - p);
    const int q0 = qt * 64 + wq * 16;

    const size_t kbase  = (size_t)b * S_LEN * D_MODEL + hd;
    const size_t vtbase = (size_t)bh * 64 * S_LEN;
    u16* Pw = &P_lds[w * 1024];

    const f32x4 ZERO = {0.f, 0.f, 0.f, 0.f};
    const f32x4 NEGI = {-1e30f, -1e30f, -1e30f, -1e30f};

    // staging: each of 512 threads stages one 16B unit of K and one of V
    const int rK = tid >> 3;
    const int uK = ((tid & 7) ^ (rK & 7)) * 8;

    const size_t qrow = ((size_t)b * S_LEN + q0 + c16) * D_MODEL + hd;
    const bf16x8 qf0 = *reinterpret_cast<const bf16x8*>(Qb + qrow + g * 8);
    const bf16x8 qf1 = *reinterpret_cast<const bf16x8*>(Qb + qrow + 32 + g * 8);

    f32x4 acc[4];
    #pragma unroll
    for (int dt = 0; dt < 4; ++dt) acc[dt] = ZERO;
    float m = -1e30f, lp = 0.f;          // per-lane: row q=c16; lp = partial l over lane's j-cols

    const int nt = 32 - p;               // iterations (long group's tile count)

    // prologue: stage tile 0 into buf 0
    gload16(Kb + kbase + (size_t)rK * D_MODEL + uK, &K_lds[0][tid * 8]);
    gload16(VT + vtbase + (size_t)rK * S_LEN + uK,  &V_lds[0][tid * 8]);
    __syncthreads();

    int cur = 0;
    for (int jt = 0; jt < nt; ++jt) {
        // ---- prefetch next tile into the other buffer (overlaps with compute below) ----
        if (jt + 1 < nt) {
            const int j0n = (jt + 1) * 64;
            gload16(Kb + kbase + (size_t)(j0n + rK) * D_MODEL + uK, &K_lds[cur ^ 1][tid * 8]);
            gload16(VT + vtbase + (size_t)rK * S_LEN + j0n + uK,    &V_lds[cur ^ 1][tid * 8]);
        }

        if (jt <= qt) {
            const bool dtile = (jt == qt);
            const u16* kl = K_lds[cur];
            const u16* vl = V_lds[cur];

            // ---- QK^T swapped: st[kt][r] = S[q=c16][j = kt*16 + g*4 + r] (log2 domain) ----
            f32x4 st[4];
            __builtin_amdgcn_s_setprio(1);
            #pragma unroll
            for (int kt = 0; kt < 4; ++kt) {
                if (dtile && kt > wq) { st[kt] = NEGI; continue; }
                const int row = kt * 16 + c16;
                const bf16x8 kf0 = *reinterpret_cast<const bf16x8*>(
                    &kl[row * 64 + ((g ^ (row & 7)) << 3)]);
                const bf16x8 kf1 = *reinterpret_cast<const bf16x8*>(
                    &kl[row * 64 + (((4 + g) ^ (row & 7)) << 3)]);
                f32x4 t = MFMA16(kf0, qf0, ZERO, 0, 0, 0);
                t = MFMA16(kf1, qf1, t, 0, 0, 0);
                if (dtile && kt == wq) {
                    #pragma unroll
                    for (int r = 0; r < 4; ++r)
                        if (g * 4 + r > c16) t[r] = -1e30f;
                }
                st[kt] = t;
            }
            __builtin_amdgcn_s_setprio(0);

            // ---- in-lane row max + 2 shfl ----
            float mx = st[0][0];
            #pragma unroll
            for (int kt = 0; kt < 4; ++kt)
                #pragma unroll
                for (int r = 0; r < 4; ++r) mx = fmaxf(mx, st[kt][r]);
            mx = fmaxf(mx, __shfl_xor(mx, 16));
            mx = fmaxf(mx, __shfl_xor(mx, 32));

            // ---- defer-max rescale (rare) ----
            if (__any(mx > m + 11.5f)) {
                const float mn = fmaxf(m, mx);
                const float co = __builtin_amdgcn_exp2f(m - mn);
                lp *= co;
                m = mn;
                float cor[4];
                #pragma unroll
                for (int r = 0; r < 4; ++r) cor[r] = __shfl(co, g * 4 + r);
                #pragma unroll
                for (int dt = 0; dt < 4; ++dt)
                    #pragma unroll
                    for (int r = 0; r < 4; ++r) acc[dt][r] *= cor[r];
            }

            // ---- p = exp2(s - m); l partial in-lane; P -> LDS via cvt_pk + b64 ----
            float tsum = 0.f;
            #pragma unroll
            for (int kt = 0; kt < 4; ++kt) {
                const float p0 = __builtin_amdgcn_exp2f(st[kt][0] - m);
                const float p1 = __builtin_amdgcn_exp2f(st[kt][1] - m);
                const float p2 = __builtin_amdgcn_exp2f(st[kt][2] - m);
                const float p3 = __builtin_amdgcn_exp2f(st[kt][3] - m);
                tsum += (p0 + p1) + (p2 + p3);
                uint2 pw;
                pw.x = cvtpk(p0, p1);
                pw.y = cvtpk(p2, p3);
                const int u = kt * 2 + (g >> 1);
                *reinterpret_cast<uint2*>(
                    &Pw[c16 * 64 + ((u ^ (c16 & 7)) << 3) + (g & 1) * 4]) = pw;
            }
            lp += tsum;

            // DS-ordering fence: P writes above may not swap with P reads below.
            __builtin_amdgcn_sched_barrier(0x7F);

            // ---- PV: acc[dt] += P[16x32] * V[32x16] ----
            __builtin_amdgcn_s_setprio(1);
            #pragma unroll
            for (int c32 = 0; c32 < 2; ++c32) {
                if (dtile && c32 == 1 && wq < 2) continue;
                const bf16x8 pf = *reinterpret_cast<const bf16x8*>(
                    &Pw[c16 * 64 + (((c32 * 4 + g) ^ (c16 & 7)) << 3)]);
                #pragma unroll
                for (int dt = 0; dt < 4; ++dt) {
                    const int vrow = dt * 16 + c16;
                    const bf16x8 vf = *reinterpret_cast<const bf16x8*>(
                        &vl[vrow * 64 + (((c32 * 4 + g) ^ (vrow & 7)) << 3)]);
                    acc[dt] = MFMA16(pf, vf, acc[dt], 0, 0, 0);
                }
            }
            __builtin_amdgcn_s_setprio(0);

            // DS-ordering fence: this tile's P reads may not swap with next tile's writes.
            __builtin_amdgcn_sched_barrier(0x7F);
        }

        __syncthreads();                 // prefetch DMAs drained + all waves done with cur
        cur ^= 1;
    }

    // ---- epilogue: cross-lane l reduce (deferred), write O ----
    float lt = lp + __shfl_xor(lp, 16);
    lt += __shfl_xor(lt, 32);
    const float inv = 1.f / lt;
    float invr[4];
    #pragma unroll
    for (int r = 0; r < 4; ++r) invr[r] = __shfl(inv, g * 4 + r);

    #pragma unroll
    for (int dt = 0; dt < 4; ++dt) {
        #pragma unroll
        for (int r = 0; r < 4; ++r) {
            const size_t orow =
                ((size_t)b * S_LEN + q0 + g * 4 + r) * D_MODEL + hd + dt * 16 + c16;
            AO[orow] = f2bf(acc[dt][r] * invr[r]);
        }
    }
}

extern "C" void kernel_launch(void* const* d_in, const int* in_sizes, int n_in,
                              void* d_out, int out_size, void* d_ws, size_t ws_size,
                              hipStream_t stream) {
    const float* x  = (const float*)d_in[0];
    // d_in[1] = causal mask: applied structurally — not read.
    const float* Wq = (const float*)d_in[2];
    const float* bq = (const float*)d_in[3];
    const float* Wk = (const float*)d_in[4];
    const float* bk = (const float*)d_in[5];
    const float* Wv = (const float*)d_in[6];
    const float* bv = (const float*)d_in[7];
    const float* Wo = (const float*)d_in[8];
    const float* bo = (const float*)d_in[9];
    float* out = (float*)d_out;

    const int M = BATCH * S_LEN;              // 8192
    const size_t tsz = (size_t)M * D_MODEL;
    const size_t wsz = (size_t)D_MODEL * D_MODEL;

    u16* xb  = (u16*)d_ws;
    u16* Qb  = xb + tsz;
    u16* Kb  = Qb + tsz;
    u16* VT  = Kb + tsz;       // V projection written directly transposed
    u16* AO  = VT + tsz;
    u16* WTq = AO + tsz;
    u16* WTk = WTq + wsz;
    u16* WTv = WTk + wsz;
    u16* WTo = WTv + wsz;

    convert_x<<<(int)(tsz / (256 * 8)), 256, 0, stream>>>(x, xb);
    transpose_w<<<dim3(16, 16, 4), 256, 0, stream>>>(
        Wq, Wk, Wv, Wo, WTq, WTk, WTv, WTo);

    gemm_qkv<<<dim3(8, 64, 3), 256, 0, stream>>>(
        xb, WTq, WTk, WTv, bq, bk, bv, Qb, Kb, VT);

    flash_attn<<<1024, 512, 0, stream>>>(Qb, Kb, VT, AO);

    gemm_out<<<dim3(8, 64), 256, 0, stream>>>(AO, WTo, bo, out);
}

// Round 13
// 194.655 us; speedup vs baseline: 1.7995x; 1.0080x over previous
//
#include <hip/hip_runtime.h>
#include <hip/hip_bf16.h>

#define D_MODEL 1024
#define NUM_HEADS 16
#define D_K 64
#define S_LEN 2048
#define BATCH 4

typedef unsigned short u16;
typedef __attribute__((ext_vector_type(8))) short bf16x8;
typedef __attribute__((ext_vector_type(4))) float f32x4;

#define MFMA16 __builtin_amdgcn_mfma_f32_16x16x32_bf16

// fold attn scale + ln2 conversion into the Q projection: 0.125 * log2(e)
#define Q_SCALE 0.18033688011112042f

__device__ __forceinline__ float bf2f(u16 u) {
    union { unsigned int i; float f; } v; v.i = ((unsigned int)u) << 16; return v.f;
}
__device__ __forceinline__ u16 f2bf(float f) {
    union { unsigned int i; float f; } v; v.f = f;
    unsigned int x = v.i;
    return (u16)((x + 0x7FFFu + ((x >> 16) & 1u)) >> 16); // round-nearest-even
}
// packed f32x2 -> bf16x2 (RNE), single HW op
__device__ __forceinline__ unsigned int cvtpk(float lo, float hi) {
    unsigned int r;
    asm("v_cvt_pk_bf16_f32 %0, %1, %2" : "=v"(r) : "v"(lo), "v"(hi));
    return r;
}

__device__ __forceinline__ void gload16(const u16* g, u16* l) {
    __builtin_amdgcn_global_load_lds(
        (const __attribute__((address_space(1))) unsigned int*)g,
        (__attribute__((address_space(3))) unsigned int*)l, 16, 0, 0);
}

// ---------------- prep (merged): blocks 0..4095 convert x fp32->bf16;
//                  blocks 4096..5119 transpose W[k][n] fp32 -> WT[n][k] bf16 ----------------
__global__ __launch_bounds__(256) void prep_kernel(
    const float* __restrict__ x, u16* __restrict__ xb,
    const float* __restrict__ W0, const float* __restrict__ W1,
    const float* __restrict__ W2, const float* __restrict__ W3,
    u16* __restrict__ T0, u16* __restrict__ T1,
    u16* __restrict__ T2, u16* __restrict__ T3)
{
    const int blk = blockIdx.x;
    const int tid = threadIdx.x;

    if (blk < 4096) {
        const size_t i = ((size_t)blk * 256 + tid) * 8;
        float4 a = *reinterpret_cast<const float4*>(x + i);
        float4 b = *reinterpret_cast<const float4*>(x + i + 4);
        bf16x8 o;
        o[0] = (short)f2bf(a.x); o[1] = (short)f2bf(a.y);
        o[2] = (short)f2bf(a.z); o[3] = (short)f2bf(a.w);
        o[4] = (short)f2bf(b.x); o[5] = (short)f2bf(b.y);
        o[6] = (short)f2bf(b.z); o[7] = (short)f2bf(b.w);
        *reinterpret_cast<bf16x8*>(xb + i) = o;
        return;
    }

    __shared__ u16 S[64][72];
    const int t  = blk - 4096;           // 0..1023
    const int bx = t & 15, by = (t >> 4) & 15, bz = t >> 8;
    const float* W; u16* T;
    switch (bz) {
        case 0:  W = W0; T = T0; break;
        case 1:  W = W1; T = T1; break;
        case 2:  W = W2; T = T2; break;
        default: W = W3; T = T3; break;
    }
    const int k0 = by * 64, n0 = bx * 64;

    const int k = tid >> 2, nb = (tid & 3) * 16;
    #pragma unroll
    for (int c = 0; c < 4; ++c) {
        float4 v = *reinterpret_cast<const float4*>(
            W + (size_t)(k0 + k) * D_MODEL + n0 + nb + c * 4);
        S[nb + c * 4 + 0][k] = f2bf(v.x);
        S[nb + c * 4 + 1][k] = f2bf(v.y);
        S[nb + c * 4 + 2][k] = f2bf(v.z);
        S[nb + c * 4 + 3][k] = f2bf(v.w);
    }
    __syncthreads();
    const int n = tid >> 2, kb = (tid & 3) * 16;
    #pragma unroll
    for (int c = 0; c < 2; ++c) {
        bf16x8 o;
        #pragma unroll
        for (int e = 0; e < 8; ++e) o[e] = (short)S[n][kb + c * 8 + e];
        *reinterpret_cast<bf16x8*>(T + (size_t)(n0 + n) * D_MODEL + k0 + kb + c * 8) = o;
    }
}

// ---------------- MFMA GEMM: C = A[8192,1024] @ BT[1024,1024]^T + bias ----------------
// EPI: 0 = bf16 row-major, 1 = fp32 row-major, 2 = bf16 transposed-per-head
//      (EPI 2 writes VT[bh][d][j]: bh=(row>>11)*16+(col>>6), d=col&63, j=row&2047 —
//       r-index maps to consecutive j, so each (mi,ni) is one ushort4 store).
template <int EPI, typename TC>
__device__ __forceinline__ void gemm_body(
    const u16* __restrict__ A, const u16* __restrict__ BT,
    const float* __restrict__ bias, TC* __restrict__ C,
    u16* Al, u16* Bl, float oscale)
{
    const int tid = threadIdx.x;
    const int w = tid >> 6, lane = tid & 63;
    const int g = lane >> 4, c16 = lane & 15;
    const int wr = w >> 1, wc = w & 1;
    const int m0 = blockIdx.y * 128, n0 = blockIdx.x * 128;

    int rS[4], uS[4];
    #pragma unroll
    for (int i = 0; i < 4; ++i) {
        const int p = i * 256 + tid;
        rS[i] = p >> 3;
        uS[i] = ((p & 7) ^ (rS[i] & 7)) * 8;
    }

    f32x4 acc[4][4];
    #pragma unroll
    for (int mi = 0; mi < 4; ++mi)
        #pragma unroll
        for (int ni = 0; ni < 4; ++ni) acc[mi][ni] = (f32x4){0.f, 0.f, 0.f, 0.f};

    for (int k0 = 0; k0 < D_MODEL; k0 += 64) {
        #pragma unroll
        for (int i = 0; i < 4; ++i) {
            gload16(A + (size_t)(m0 + rS[i]) * D_MODEL + k0 + uS[i],
                    Al + (size_t)(i * 256 + w * 64) * 8);
            gload16(BT + (size_t)(n0 + rS[i]) * D_MODEL + k0 + uS[i],
                    Bl + (size_t)(i * 256 + w * 64) * 8);
        }
        __syncthreads();

        #pragma unroll
        for (int s = 0; s < 2; ++s) {
            bf16x8 af[4], bfr[4];
            #pragma unroll
            for (int mi = 0; mi < 4; ++mi) {
                const int r = wr * 64 + mi * 16 + c16;
                af[mi] = *reinterpret_cast<const bf16x8*>(
                    &Al[((r << 3) + ((s * 4 + g) ^ (r & 7))) * 8]);
            }
            #pragma unroll
            for (int ni = 0; ni < 4; ++ni) {
                const int r = wc * 64 + ni * 16 + c16;
                bfr[ni] = *reinterpret_cast<const bf16x8*>(
                    &Bl[((r << 3) + ((s * 4 + g) ^ (r & 7))) * 8]);
            }
            #pragma unroll
            for (int mi = 0; mi < 4; ++mi)
                #pragma unroll
                for (int ni = 0; ni < 4; ++ni)
                    acc[mi][ni] = MFMA16(af[mi], bfr[ni], acc[mi][ni], 0, 0, 0);
        }
        __syncthreads();
    }

    float bc[4];
    #pragma unroll
    for (int ni = 0; ni < 4; ++ni) bc[ni] = bias[n0 + wc * 64 + ni * 16 + c16];

    if constexpr (EPI == 2) {
        const int rowb = m0 + wr * 64 + g * 4;        // token row base (+mi*16, +r)
        const int bb = rowb >> 11;                    // batch (tile never crosses)
        #pragma unroll
        for (int mi = 0; mi < 4; ++mi) {
            const int row = rowb + mi * 16;
            const int jj = row & 2047;
            #pragma unroll
            for (int ni = 0; ni < 4; ++ni) {
                const int col = n0 + wc * 64 + ni * 16 + c16;
                ushort4 ov;
                ov.x = f2bf(acc[mi][ni][0] + bc[ni]);
                ov.y = f2bf(acc[mi][ni][1] + bc[ni]);
                ov.z = f2bf(acc[mi][ni][2] + bc[ni]);
                ov.w = f2bf(acc[mi][ni][3] + bc[ni]);
                *reinterpret_cast<ushort4*>(
                    &C[((size_t)(bb * 16 + (col >> 6)) * 64 + (col & 63)) * S_LEN + jj]) = ov;
            }
        }
    } else {
        #pragma unroll
        for (int mi = 0; mi < 4; ++mi) {
            #pragma unroll
            for (int ni = 0; ni < 4; ++ni) {
                const int col = n0 + wc * 64 + ni * 16 + c16;
                #pragma unroll
                for (int r = 0; r < 4; ++r) {
                    const int row = m0 + wr * 64 + mi * 16 + g * 4 + r;
                    const float v = (acc[mi][ni][r] + bc[ni]) * oscale;
                    if constexpr (EPI == 1) {
                        C[(size_t)row * D_MODEL + col] = v;
                    } else {
                        C[(size_t)row * D_MODEL + col] = f2bf(v);
                    }
                }
            }
        }
    }
}

__global__ __launch_bounds__(256) void gemm_qkv(
    const u16* __restrict__ A,
    const u16* __restrict__ BTq, const u16* __restrict__ BTk, const u16* __restrict__ BTv,
    const float* __restrict__ bq, const float* __restrict__ bk, const float* __restrict__ bv,
    u16* __restrict__ Cq, u16* __restrict__ Ck, u16* __restrict__ Cv)
{
    __shared__ u16 Al[128 * 64];
    __shared__ u16 Bl[128 * 64];
    switch (blockIdx.z) {
        case 0:  gemm_body<0, u16>(A, BTq, bq, Cq, Al, Bl, Q_SCALE); break;
        case 1:  gemm_body<0, u16>(A, BTk, bk, Ck, Al, Bl, 1.f);     break;
        default: gemm_body<2, u16>(A, BTv, bv, Cv, Al, Bl, 1.f);     break;  // -> VT
    }
}

__global__ __launch_bounds__(256) void gemm_out(
    const u16* __restrict__ A, const u16* __restrict__ BT,
    const float* __restrict__ bias, float* __restrict__ C)
{
    __shared__ u16 Al[128 * 64];
    __shared__ u16 Bl[128 * 64];
    gemm_body<1, float>(A, BT, bias, C, Al, Bl, 1.f);
}

// ---------------- MFMA flash attention v5 (byte-identical to round-9 passing kernel) ----------------
// 1024 blocks x 512 threads (8 waves). Block i: xcd=i&7, bh=(i&7)*8+((i>>3)&7), p=i>>6
// (LPT: p ascending => cost 32-p descending). Waves 0-3 own q-tile p, waves 4-7 own 31-p;
// one K/V stage per jt serves both. Prefetch of tile jt+1 issued BEFORE computing jt.
__global__ __launch_bounds__(512, 6) void flash_attn(
    const u16* __restrict__ Qb, const u16* __restrict__ Kb,
    const u16* __restrict__ VT, u16* __restrict__ AO)
{
    __shared__ u16 K_lds[2][4096];       // [buf][key j][d], XOR-swizzled 16B units
    __shared__ u16 V_lds[2][4096];       // [buf][d][key j], XOR-swizzled
    __shared__ u16 P_lds[8 * 1024];      // per-wave [q][j], XOR-swizzled

    const int i  = blockIdx.x;
    const int bh = (i & 7) * 8 + ((i >> 3) & 7);
    const int p  = i >> 6;               // 0..15
    const int b  = bh >> 4, h = bh & 15, hd = h * 64;

    const int tid = threadIdx.x;
    const int w = tid >> 6, lane = tid & 63;
    const int wq = w & 3;
    const int g = lane >> 4, c16 = lane & 15;

    const int qt = (w < 4) ? p : (31 - p);
    const int q0 = qt * 64 + wq * 16;

    const size_t kbase  = (size_t)b * S_LEN * D_MODEL + hd;
    const size_t vtbase = (size_t)bh * 64 * S_LEN;
    u16* Pw = &P_lds[w * 1024];

    const f32x4 ZERO = {0.f, 0.f, 0.f, 0.f};
    const f32x4 NEGI = {-1e30f, -1e30f, -1e30f, -1e30f};

    // staging: each of 512 threads stages one 16B unit of K and one of V
    const int rK = tid >> 3;
    const int uK = ((tid & 7) ^ (rK & 7)) * 8;

    const size_t qrow = ((size_t)b * S_LEN + q0 + c16) * D_MODEL + hd;
    const bf16x8 qf0 = *reinterpret_cast<const bf16x8*>(Qb + qrow + g * 8);
    const bf16x8 qf1 = *reinterpret_cast<const bf16x8*>(Qb + qrow + 32 + g * 8);

    f32x4 acc[4];
    #pragma unroll
    for (int dt = 0; dt < 4; ++dt) acc[dt] = ZERO;
    float m = -1e30f, lp = 0.f;          // per-lane: row q=c16; lp = partial l over lane's j-cols

    const int nt = 32 - p;               // iterations (long group's tile count)

    // prologue: stage tile 0 into buf 0
    gload16(Kb + kbase + (size_t)rK * D_MODEL + uK, &K_lds[0][tid * 8]);
    gload16(VT + vtbase + (size_t)rK * S_LEN + uK,  &V_lds[0][tid * 8]);
    __syncthreads();

    int cur = 0;
    for (int jt = 0; jt < nt; ++jt) {
        // ---- prefetch next tile into the other buffer (overlaps with compute below) ----
        if (jt + 1 < nt) {
            const int j0n = (jt + 1) * 64;
            gload16(Kb + kbase + (size_t)(j0n + rK) * D_MODEL + uK, &K_lds[cur ^ 1][tid * 8]);
            gload16(VT + vtbase + (size_t)rK * S_LEN + j0n + uK,    &V_lds[cur ^ 1][tid * 8]);
        }

        if (jt <= qt) {
            const bool dtile = (jt == qt);
            const u16* kl = K_lds[cur];
            const u16* vl = V_lds[cur];

            // ---- QK^T swapped: st[kt][r] = S[q=c16][j = kt*16 + g*4 + r] (log2 domain) ----
            f32x4 st[4];
            __builtin_amdgcn_s_setprio(1);
            #pragma unroll
            for (int kt = 0; kt < 4; ++kt) {
                if (dtile && kt > wq) { st[kt] = NEGI; continue; }
                const int row = kt * 16 + c16;
                const bf16x8 kf0 = *reinterpret_cast<const bf16x8*>(
                    &kl[row * 64 + ((g ^ (row & 7)) << 3)]);
                const bf16x8 kf1 = *reinterpret_cast<const bf16x8*>(
                    &kl[row * 64 + (((4 + g) ^ (row & 7)) << 3)]);
                f32x4 t = MFMA16(kf0, qf0, ZERO, 0, 0, 0);
                t = MFMA16(kf1, qf1, t, 0, 0, 0);
                if (dtile && kt == wq) {
                    #pragma unroll
                    for (int r = 0; r < 4; ++r)
                        if (g * 4 + r > c16) t[r] = -1e30f;
                }
                st[kt] = t;
            }
            __builtin_amdgcn_s_setprio(0);

            // ---- in-lane row max + 2 shfl ----
            float mx = st[0][0];
            #pragma unroll
            for (int kt = 0; kt < 4; ++kt)
                #pragma unroll
                for (int r = 0; r < 4; ++r) mx = fmaxf(mx, st[kt][r]);
            mx = fmaxf(mx, __shfl_xor(mx, 16));
            mx = fmaxf(mx, __shfl_xor(mx, 32));

            // ---- defer-max rescale (rare) ----
            if (__any(mx > m + 11.5f)) {
                const float mn = fmaxf(m, mx);
                const float co = __builtin_amdgcn_exp2f(m - mn);
                lp *= co;
                m = mn;
                float cor[4];
                #pragma unroll
                for (int r = 0; r < 4; ++r) cor[r] = __shfl(co, g * 4 + r);
                #pragma unroll
                for (int dt = 0; dt < 4; ++dt)
                    #pragma unroll
                    for (int r = 0; r < 4; ++r) acc[dt][r] *= cor[r];
            }

            // ---- p = exp2(s - m); l partial in-lane; P -> LDS via cvt_pk + b64 ----
            float tsum = 0.f;
            #pragma unroll
            for (int kt = 0; kt < 4; ++kt) {
                const float p0 = __builtin_amdgcn_exp2f(st[kt][0] - m);
                const float p1 = __builtin_amdgcn_exp2f(st[kt][1] - m);
                const float p2 = __builtin_amdgcn_exp2f(st[kt][2] - m);
                const float p3 = __builtin_amdgcn_exp2f(st[kt][3] - m);
                tsum += (p0 + p1) + (p2 + p3);
                uint2 pw;
                pw.x = cvtpk(p0, p1);
                pw.y = cvtpk(p2, p3);
                const int u = kt * 2 + (g >> 1);
                *reinterpret_cast<uint2*>(
                    &Pw[c16 * 64 + ((u ^ (c16 & 7)) << 3) + (g & 1) * 4]) = pw;
            }
            lp += tsum;

            // DS-ordering fence: P writes above may not swap with P reads below.
            __builtin_amdgcn_sched_barrier(0x7F);

            // ---- PV: acc[dt] += P[16x32] * V[32x16] ----
            __builtin_amdgcn_s_setprio(1);
            #pragma unroll
            for (int c32 = 0; c32 < 2; ++c32) {
                if (dtile && c32 == 1 && wq < 2) continue;
                const bf16x8 pf = *reinterpret_cast<const bf16x8*>(
                    &Pw[c16 * 64 + (((c32 * 4 + g) ^ (c16 & 7)) << 3)]);
                #pragma unroll
                for (int dt = 0; dt < 4; ++dt) {
                    const int vrow = dt * 16 + c16;
                    const bf16x8 vf = *reinterpret_cast<const bf16x8*>(
                        &vl[vrow * 64 + (((c32 * 4 + g) ^ (vrow & 7)) << 3)]);
                    acc[dt] = MFMA16(pf, vf, acc[dt], 0, 0, 0);
                }
            }
            __builtin_amdgcn_s_setprio(0);

            // DS-ordering fence: this tile's P reads may not swap with next tile's writes.
            __builtin_amdgcn_sched_barrier(0x7F);
        }

        __syncthreads();                 // prefetch DMAs drained + all waves done with cur
        cur ^= 1;
    }

    // ---- epilogue: cross-lane l reduce (deferred), write O ----
    float lt = lp + __shfl_xor(lp, 16);
    lt += __shfl_xor(lt, 32);
    const float inv = 1.f / lt;
    float invr[4];
    #pragma unroll
    for (int r = 0; r < 4; ++r) invr[r] = __shfl(inv, g * 4 + r);

    #pragma unroll
    for (int dt = 0; dt < 4; ++dt) {
        #pragma unroll
        for (int r = 0; r < 4; ++r) {
            const size_t orow =
                ((size_t)b * S_LEN + q0 + g * 4 + r) * D_MODEL + hd + dt * 16 + c16;
            AO[orow] = f2bf(acc[dt][r] * invr[r]);
        }
    }
}

extern "C" void kernel_launch(void* const* d_in, const int* in_sizes, int n_in,
                              void* d_out, int out_size, void* d_ws, size_t ws_size,
                              hipStream_t stream) {
    const float* x  = (const float*)d_in[0];
    // d_in[1] = causal mask: applied structurally — not read.
    const float* Wq = (const float*)d_in[2];
    const float* bq = (const float*)d_in[3];
    const float* Wk = (const float*)d_in[4];
    const float* bk = (const float*)d_in[5];
    const float* Wv = (const float*)d_in[6];
    const float* bv = (const float*)d_in[7];
    const float* Wo = (const float*)d_in[8];
    const float* bo = (const float*)d_in[9];
    float* out = (float*)d_out;

    const int M = BATCH * S_LEN;              // 8192
    const size_t tsz = (size_t)M * D_MODEL;
    const size_t wsz = (size_t)D_MODEL * D_MODEL;

    u16* xb  = (u16*)d_ws;
    u16* Qb  = xb + tsz;
    u16* Kb  = Qb + tsz;
    u16* VT  = Kb + tsz;       // V projection written directly transposed
    u16* AO  = VT + tsz;
    u16* WTq = AO + tsz;
    u16* WTk = WTq + wsz;
    u16* WTv = WTk + wsz;
    u16* WTo = WTv + wsz;

    prep_kernel<<<5120, 256, 0, stream>>>(
        x, xb, Wq, Wk, Wv, Wo, WTq, WTk, WTv, WTo);

    gemm_qkv<<<dim3(8, 64, 3), 256, 0, stream>>>(
        xb, WTq, WTk, WTv, bq, bk, bv, Qb, Kb, VT);

    flash_attn<<<1024, 512, 0, stream>>>(Qb, Kb, VT, AO);

    gemm_out<<<dim3(8, 64), 256, 0, stream>>>(AO, WTo, bo, out);
}

// Round 14
// 184.146 us; speedup vs baseline: 1.9022x; 1.0571x over previous
//
#include <hip/hip_runtime.h>
#include <hip/hip_bf16.h>

#define D_MODEL 1024
#define NUM_HEADS 16
#define D_K 64
#define S_LEN 2048
#define BATCH 4

typedef unsigned short u16;
typedef __attribute__((ext_vector_type(8))) short bf16x8;
typedef __attribute__((ext_vector_type(4))) float f32x4;

#define MFMA16 __builtin_amdgcn_mfma_f32_16x16x32_bf16

// fold attn scale + ln2 conversion into the Q projection: 0.125 * log2(e)
#define Q_SCALE 0.18033688011112042f

__device__ __forceinline__ float bf2f(u16 u) {
    union { unsigned int i; float f; } v; v.i = ((unsigned int)u) << 16; return v.f;
}
__device__ __forceinline__ u16 f2bf(float f) {
    union { unsigned int i; float f; } v; v.f = f;
    unsigned int x = v.i;
    return (u16)((x + 0x7FFFu + ((x >> 16) & 1u)) >> 16); // round-nearest-even
}
// packed f32x2 -> bf16x2 (RNE), single HW op
__device__ __forceinline__ unsigned int cvtpk(float lo, float hi) {
    unsigned int r;
    asm("v_cvt_pk_bf16_f32 %0, %1, %2" : "=v"(r) : "v"(lo), "v"(hi));
    return r;
}

__device__ __forceinline__ void gload16(const u16* g, u16* l) {
    __builtin_amdgcn_global_load_lds(
        (const __attribute__((address_space(1))) unsigned int*)g,
        (__attribute__((address_space(3))) unsigned int*)l, 16, 0, 0);
}

// ---------------- prep (merged): blocks 0..4095 convert x fp32->bf16;
//                  blocks 4096..5119 transpose W[k][n] fp32 -> WT[n][k] bf16 ----------------
__global__ __launch_bounds__(256) void prep_kernel(
    const float* __restrict__ x, u16* __restrict__ xb,
    const float* __restrict__ W0, const float* __restrict__ W1,
    const float* __restrict__ W2, const float* __restrict__ W3,
    u16* __restrict__ T0, u16* __restrict__ T1,
    u16* __restrict__ T2, u16* __restrict__ T3)
{
    const int blk = blockIdx.x;
    const int tid = threadIdx.x;

    if (blk < 4096) {
        const size_t i = ((size_t)blk * 256 + tid) * 8;
        float4 a = *reinterpret_cast<const float4*>(x + i);
        float4 b = *reinterpret_cast<const float4*>(x + i + 4);
        bf16x8 o;
        o[0] = (short)f2bf(a.x); o[1] = (short)f2bf(a.y);
        o[2] = (short)f2bf(a.z); o[3] = (short)f2bf(a.w);
        o[4] = (short)f2bf(b.x); o[5] = (short)f2bf(b.y);
        o[6] = (short)f2bf(b.z); o[7] = (short)f2bf(b.w);
        *reinterpret_cast<bf16x8*>(xb + i) = o;
        return;
    }

    __shared__ u16 S[64][72];
    const int t  = blk - 4096;           // 0..1023
    const int bx = t & 15, by = (t >> 4) & 15, bz = t >> 8;
    const float* W; u16* T;
    switch (bz) {
        case 0:  W = W0; T = T0; break;
        case 1:  W = W1; T = T1; break;
        case 2:  W = W2; T = T2; break;
        default: W = W3; T = T3; break;
    }
    const int k0 = by * 64, n0 = bx * 64;

    const int k = tid >> 2, nb = (tid & 3) * 16;
    #pragma unroll
    for (int c = 0; c < 4; ++c) {
        float4 v = *reinterpret_cast<const float4*>(
            W + (size_t)(k0 + k) * D_MODEL + n0 + nb + c * 4);
        S[nb + c * 4 + 0][k] = f2bf(v.x);
        S[nb + c * 4 + 1][k] = f2bf(v.y);
        S[nb + c * 4 + 2][k] = f2bf(v.z);
        S[nb + c * 4 + 3][k] = f2bf(v.w);
    }
    __syncthreads();
    const int n = tid >> 2, kb = (tid & 3) * 16;
    #pragma unroll
    for (int c = 0; c < 2; ++c) {
        bf16x8 o;
        #pragma unroll
        for (int e = 0; e < 8; ++e) o[e] = (short)S[n][kb + c * 8 + e];
        *reinterpret_cast<bf16x8*>(T + (size_t)(n0 + n) * D_MODEL + k0 + kb + c * 8) = o;
    }
}

// ---------------- MFMA GEMM: C = A[8192,1024] @ BT[1024,1024]^T + bias ----------------
// EPI: 0 = bf16 row-major, 1 = fp32 row-major, 2 = bf16 transposed-per-head
//      (EPI 2 writes VT[bh][d][j]: bh=(row>>11)*16+(col>>6), d=col&63, j=row&2047).
// XCD-aware tile swizzle (T1): flat = y*8+x (dispatch order, 512 total % 8 == 0) ->
// tile = (flat&7)*64 + (flat>>3). Blocks landing on XCD x get contiguous tile range
// x*64..x*64+63 = 8 m-panels x all 8 n-tiles: per-XCD L2 holds one 2MB A-panel (8x
// reuse) + 2MB B. Pure bijection — correctness-independent.
template <int EPI, typename TC>
__device__ __forceinline__ void gemm_body(
    const u16* __restrict__ A, const u16* __restrict__ BT,
    const float* __restrict__ bias, TC* __restrict__ C,
    u16* Al, u16* Bl, float oscale)
{
    const int tid = threadIdx.x;
    const int w = tid >> 6, lane = tid & 63;
    const int g = lane >> 4, c16 = lane & 15;
    const int wr = w >> 1, wc = w & 1;

    const int flat = blockIdx.y * 8 + blockIdx.x;          // 0..511
    const int tile = (flat & 7) * 64 + (flat >> 3);        // bijective remap
    const int m0 = (tile >> 3) * 128, n0 = (tile & 7) * 128;

    int rS[4], uS[4];
    #pragma unroll
    for (int i = 0; i < 4; ++i) {
        const int p = i * 256 + tid;
        rS[i] = p >> 3;
        uS[i] = ((p & 7) ^ (rS[i] & 7)) * 8;
    }

    f32x4 acc[4][4];
    #pragma unroll
    for (int mi = 0; mi < 4; ++mi)
        #pragma unroll
        for (int ni = 0; ni < 4; ++ni) acc[mi][ni] = (f32x4){0.f, 0.f, 0.f, 0.f};

    for (int k0 = 0; k0 < D_MODEL; k0 += 64) {
        #pragma unroll
        for (int i = 0; i < 4; ++i) {
            gload16(A + (size_t)(m0 + rS[i]) * D_MODEL + k0 + uS[i],
                    Al + (size_t)(i * 256 + w * 64) * 8);
            gload16(BT + (size_t)(n0 + rS[i]) * D_MODEL + k0 + uS[i],
                    Bl + (size_t)(i * 256 + w * 64) * 8);
        }
        __syncthreads();

        #pragma unroll
        for (int s = 0; s < 2; ++s) {
            bf16x8 af[4], bfr[4];
            #pragma unroll
            for (int mi = 0; mi < 4; ++mi) {
                const int r = wr * 64 + mi * 16 + c16;
                af[mi] = *reinterpret_cast<const bf16x8*>(
                    &Al[((r << 3) + ((s * 4 + g) ^ (r & 7))) * 8]);
            }
            #pragma unroll
            for (int ni = 0; ni < 4; ++ni) {
                const int r = wc * 64 + ni * 16 + c16;
                bfr[ni] = *reinterpret_cast<const bf16x8*>(
                    &Bl[((r << 3) + ((s * 4 + g) ^ (r & 7))) * 8]);
            }
            #pragma unroll
            for (int mi = 0; mi < 4; ++mi)
                #pragma unroll
                for (int ni = 0; ni < 4; ++ni)
                    acc[mi][ni] = MFMA16(af[mi], bfr[ni], acc[mi][ni], 0, 0, 0);
        }
        __syncthreads();
    }

    float bc[4];
    #pragma unroll
    for (int ni = 0; ni < 4; ++ni) bc[ni] = bias[n0 + wc * 64 + ni * 16 + c16];

    if constexpr (EPI == 2) {
        const int rowb = m0 + wr * 64 + g * 4;        // token row base (+mi*16, +r)
        const int bb = rowb >> 11;                    // batch (tile never crosses)
        #pragma unroll
        for (int mi = 0; mi < 4; ++mi) {
            const int row = rowb + mi * 16;
            const int jj = row & 2047;
            #pragma unroll
            for (int ni = 0; ni < 4; ++ni) {
                const int col = n0 + wc * 64 + ni * 16 + c16;
                ushort4 ov;
                ov.x = f2bf(acc[mi][ni][0] + bc[ni]);
                ov.y = f2bf(acc[mi][ni][1] + bc[ni]);
                ov.z = f2bf(acc[mi][ni][2] + bc[ni]);
                ov.w = f2bf(acc[mi][ni][3] + bc[ni]);
                *reinterpret_cast<ushort4*>(
                    &C[((size_t)(bb * 16 + (col >> 6)) * 64 + (col & 63)) * S_LEN + jj]) = ov;
            }
        }
    } else {
        #pragma unroll
        for (int mi = 0; mi < 4; ++mi) {
            #pragma unroll
            for (int ni = 0; ni < 4; ++ni) {
                const int col = n0 + wc * 64 + ni * 16 + c16;
                #pragma unroll
                for (int r = 0; r < 4; ++r) {
                    const int row = m0 + wr * 64 + mi * 16 + g * 4 + r;
                    const float v = (acc[mi][ni][r] + bc[ni]) * oscale;
                    if constexpr (EPI == 1) {
                        C[(size_t)row * D_MODEL + col] = v;
                    } else {
                        C[(size_t)row * D_MODEL + col] = f2bf(v);
                    }
                }
            }
        }
    }
}

__global__ __launch_bounds__(256) void gemm_qkv(
    const u16* __restrict__ A,
    const u16* __restrict__ BTq, const u16* __restrict__ BTk, const u16* __restrict__ BTv,
    const float* __restrict__ bq, const float* __restrict__ bk, const float* __restrict__ bv,
    u16* __restrict__ Cq, u16* __restrict__ Ck, u16* __restrict__ Cv)
{
    __shared__ u16 Al[128 * 64];
    __shared__ u16 Bl[128 * 64];
    switch (blockIdx.z) {
        case 0:  gemm_body<0, u16>(A, BTq, bq, Cq, Al, Bl, Q_SCALE); break;
        case 1:  gemm_body<0, u16>(A, BTk, bk, Ck, Al, Bl, 1.f);     break;
        default: gemm_body<2, u16>(A, BTv, bv, Cv, Al, Bl, 1.f);     break;  // -> VT
    }
}

__global__ __launch_bounds__(256) void gemm_out(
    const u16* __restrict__ A, const u16* __restrict__ BT,
    const float* __restrict__ bias, float* __restrict__ C)
{
    __shared__ u16 Al[128 * 64];
    __shared__ u16 Bl[128 * 64];
    gemm_body<1, float>(A, BT, bias, C, Al, Bl, 1.f);
}

// ---------------- MFMA flash attention v5 (byte-identical to round-9 passing kernel) ----------------
// 1024 blocks x 512 threads (8 waves). Block i: xcd=i&7, bh=(i&7)*8+((i>>3)&7), p=i>>6
// (LPT: p ascending => cost 32-p descending). Waves 0-3 own q-tile p, waves 4-7 own 31-p;
// one K/V stage per jt serves both. Prefetch of tile jt+1 issued BEFORE computing jt.
__global__ __launch_bounds__(512, 6) void flash_attn(
    const u16* __restrict__ Qb, const u16* __restrict__ Kb,
    const u16* __restrict__ VT, u16* __restrict__ AO)
{
    __shared__ u16 K_lds[2][4096];       // [buf][key j][d], XOR-swizzled 16B units
    __shared__ u16 V_lds[2][4096];       // [buf][d][key j], XOR-swizzled
    __shared__ u16 P_lds[8 * 1024];      // per-wave [q][j], XOR-swizzled

    const int i  = blockIdx.x;
    const int bh = (i & 7) * 8 + ((i >> 3) & 7);
    const int p  = i >> 6;               // 0..15
    const int b  = bh >> 4, h = bh & 15, hd = h * 64;

    const int tid = threadIdx.x;
    const int w = tid >> 6, lane = tid & 63;
    const int wq = w & 3;
    const int g = lane >> 4, c16 = lane & 15;

    const int qt = (w < 4) ? p : (31 - p);
    const int q0 = qt * 64 + wq * 16;

    const size_t kbase  = (size_t)b * S_LEN * D_MODEL + hd;
    const size_t vtbase = (size_t)bh * 64 * S_LEN;
    u16* Pw = &P_lds[w * 1024];

    const f32x4 ZERO = {0.f, 0.f, 0.f, 0.f};
    const f32x4 NEGI = {-1e30f, -1e30f, -1e30f, -1e30f};

    // staging: each of 512 threads stages one 16B unit of K and one of V
    const int rK = tid >> 3;
    const int uK = ((tid & 7) ^ (rK & 7)) * 8;

    const size_t qrow = ((size_t)b * S_LEN + q0 + c16) * D_MODEL + hd;
    const bf16x8 qf0 = *reinterpret_cast<const bf16x8*>(Qb + qrow + g * 8);
    const bf16x8 qf1 = *reinterpret_cast<const bf16x8*>(Qb + qrow + 32 + g * 8);

    f32x4 acc[4];
    #pragma unroll
    for (int dt = 0; dt < 4; ++dt) acc[dt] = ZERO;
    float m = -1e30f, lp = 0.f;          // per-lane: row q=c16; lp = partial l over lane's j-cols

    const int nt = 32 - p;               // iterations (long group's tile count)

    // prologue: stage tile 0 into buf 0
    gload16(Kb + kbase + (size_t)rK * D_MODEL + uK, &K_lds[0][tid * 8]);
    gload16(VT + vtbase + (size_t)rK * S_LEN + uK,  &V_lds[0][tid * 8]);
    __syncthreads();

    int cur = 0;
    for (int jt = 0; jt < nt; ++jt) {
        // ---- prefetch next tile into the other buffer (overlaps with compute below) ----
        if (jt + 1 < nt) {
            const int j0n = (jt + 1) * 64;
            gload16(Kb + kbase + (size_t)(j0n + rK) * D_MODEL + uK, &K_lds[cur ^ 1][tid * 8]);
            gload16(VT + vtbase + (size_t)rK * S_LEN + j0n + uK,    &V_lds[cur ^ 1][tid * 8]);
        }

        if (jt <= qt) {
            const bool dtile = (jt == qt);
            const u16* kl = K_lds[cur];
            const u16* vl = V_lds[cur];

            // ---- QK^T swapped: st[kt][r] = S[q=c16][j = kt*16 + g*4 + r] (log2 domain) ----
            f32x4 st[4];
            __builtin_amdgcn_s_setprio(1);
            #pragma unroll
            for (int kt = 0; kt < 4; ++kt) {
                if (dtile && kt > wq) { st[kt] = NEGI; continue; }
                const int row = kt * 16 + c16;
                const bf16x8 kf0 = *reinterpret_cast<const bf16x8*>(
                    &kl[row * 64 + ((g ^ (row & 7)) << 3)]);
                const bf16x8 kf1 = *reinterpret_cast<const bf16x8*>(
                    &kl[row * 64 + (((4 + g) ^ (row & 7)) << 3)]);
                f32x4 t = MFMA16(kf0, qf0, ZERO, 0, 0, 0);
                t = MFMA16(kf1, qf1, t, 0, 0, 0);
                if (dtile && kt == wq) {
                    #pragma unroll
                    for (int r = 0; r < 4; ++r)
                        if (g * 4 + r > c16) t[r] = -1e30f;
                }
                st[kt] = t;
            }
            __builtin_amdgcn_s_setprio(0);

            // ---- in-lane row max + 2 shfl ----
            float mx = st[0][0];
            #pragma unroll
            for (int kt = 0; kt < 4; ++kt)
                #pragma unroll
                for (int r = 0; r < 4; ++r) mx = fmaxf(mx, st[kt][r]);
            mx = fmaxf(mx, __shfl_xor(mx, 16));
            mx = fmaxf(mx, __shfl_xor(mx, 32));

            // ---- defer-max rescale (rare) ----
            if (__any(mx > m + 11.5f)) {
                const float mn = fmaxf(m, mx);
                const float co = __builtin_amdgcn_exp2f(m - mn);
                lp *= co;
                m = mn;
                float cor[4];
                #pragma unroll
                for (int r = 0; r < 4; ++r) cor[r] = __shfl(co, g * 4 + r);
                #pragma unroll
                for (int dt = 0; dt < 4; ++dt)
                    #pragma unroll
                    for (int r = 0; r < 4; ++r) acc[dt][r] *= cor[r];
            }

            // ---- p = exp2(s - m); l partial in-lane; P -> LDS via cvt_pk + b64 ----
            float tsum = 0.f;
            #pragma unroll
            for (int kt = 0; kt < 4; ++kt) {
                const float p0 = __builtin_amdgcn_exp2f(st[kt][0] - m);
                const float p1 = __builtin_amdgcn_exp2f(st[kt][1] - m);
                const float p2 = __builtin_amdgcn_exp2f(st[kt][2] - m);
                const float p3 = __builtin_amdgcn_exp2f(st[kt][3] - m);
                tsum += (p0 + p1) + (p2 + p3);
                uint2 pw;
                pw.x = cvtpk(p0, p1);
                pw.y = cvtpk(p2, p3);
                const int u = kt * 2 + (g >> 1);
                *reinterpret_cast<uint2*>(
                    &Pw[c16 * 64 + ((u ^ (c16 & 7)) << 3) + (g & 1) * 4]) = pw;
            }
            lp += tsum;

            // DS-ordering fence: P writes above may not swap with P reads below.
            __builtin_amdgcn_sched_barrier(0x7F);

            // ---- PV: acc[dt] += P[16x32] * V[32x16] ----
            __builtin_amdgcn_s_setprio(1);
            #pragma unroll
            for (int c32 = 0; c32 < 2; ++c32) {
                if (dtile && c32 == 1 && wq < 2) continue;
                const bf16x8 pf = *reinterpret_cast<const bf16x8*>(
                    &Pw[c16 * 64 + (((c32 * 4 + g) ^ (c16 & 7)) << 3)]);
                #pragma unroll
                for (int dt = 0; dt < 4; ++dt) {
                    const int vrow = dt * 16 + c16;
                    const bf16x8 vf = *reinterpret_cast<const bf16x8*>(
                        &vl[vrow * 64 + (((c32 * 4 + g) ^ (vrow & 7)) << 3)]);
                    acc[dt] = MFMA16(pf, vf, acc[dt], 0, 0, 0);
                }
            }
            __builtin_amdgcn_s_setprio(0);

            // DS-ordering fence: this tile's P reads may not swap with next tile's writes.
            __builtin_amdgcn_sched_barrier(0x7F);
        }

        __syncthreads();                 // prefetch DMAs drained + all waves done with cur
        cur ^= 1;
    }

    // ---- epilogue: cross-lane l reduce (deferred), write O ----
    float lt = lp + __shfl_xor(lp, 16);
    lt += __shfl_xor(lt, 32);
    const float inv = 1.f / lt;
    float invr[4];
    #pragma unroll
    for (int r = 0; r < 4; ++r) invr[r] = __shfl(inv, g * 4 + r);

    #pragma unroll
    for (int dt = 0; dt < 4; ++dt) {
        #pragma unroll
        for (int r = 0; r < 4; ++r) {
            const size_t orow =
                ((size_t)b * S_LEN + q0 + g * 4 + r) * D_MODEL + hd + dt * 16 + c16;
            AO[orow] = f2bf(acc[dt][r] * invr[r]);
        }
    }
}

extern "C" void kernel_launch(void* const* d_in, const int* in_sizes, int n_in,
                              void* d_out, int out_size, void* d_ws, size_t ws_size,
                              hipStream_t stream) {
    const float* x  = (const float*)d_in[0];
    // d_in[1] = causal mask: applied structurally — not read.
    const float* Wq = (const float*)d_in[2];
    const float* bq = (const float*)d_in[3];
    const float* Wk = (const float*)d_in[4];
    const float* bk = (const float*)d_in[5];
    const float* Wv = (const float*)d_in[6];
    const float* bv = (const float*)d_in[7];
    const float* Wo = (const float*)d_in[8];
    const float* bo = (const float*)d_in[9];
    float* out = (float*)d_out;

    const int M = BATCH * S_LEN;              // 8192
    const size_t tsz = (size_t)M * D_MODEL;
    const size_t wsz = (size_t)D_MODEL * D_MODEL;

    u16* xb  = (u16*)d_ws;
    u16* Qb  = xb + tsz;
    u16* Kb  = Qb + tsz;
    u16* VT  = Kb + tsz;       // V projection written directly transposed
    u16* AO  = VT + tsz;
    u16* WTq = AO + tsz;
    u16* WTk = WTq + wsz;
    u16* WTv = WTk + wsz;
    u16* WTo = WTv + wsz;

    prep_kernel<<<5120, 256, 0, stream>>>(
        x, xb, Wq, Wk, Wv, Wo, WTq, WTk, WTv, WTo);

    gemm_qkv<<<dim3(8, 64, 3), 256, 0, stream>>>(
        xb, WTq, WTk, WTv, bq, bk, bv, Qb, Kb, VT);

    flash_attn<<<1024, 512, 0, stream>>>(Qb, Kb, VT, AO);

    gemm_out<<<dim3(8, 64), 256, 0, stream>>>(AO, WTo, bo, out);
}